// Round 2
// baseline (586.059 us; speedup 1.0000x reference)
//
#include <hip/hip_runtime.h>

typedef unsigned short u16;
typedef __attribute__((ext_vector_type(8))) short bf16x8;
typedef __attribute__((ext_vector_type(4))) float f32x4;
typedef __attribute__((ext_vector_type(16))) float f32x16;

typedef const __attribute__((address_space(1))) void* gptr_t;
typedef __attribute__((address_space(3))) void* lptr_t;

__device__ __forceinline__ unsigned cvtpk_bf16(float a, float b){
  unsigned r; asm("v_cvt_pk_bf16_f32 %0, %1, %2" : "=v"(r) : "v"(a), "v"(b)); return r;
}
__device__ __forceinline__ u16 f2bf(float x){ return (u16)cvtpk_bf16(x, x); }
__device__ __forceinline__ float bf2f(u16 u){ union{unsigned i; float f;} v; v.i = ((unsigned)u)<<16; return v.f; }
__device__ __forceinline__ float fexp2(float x){ float r; asm("v_exp_f32 %0, %1" : "=v"(r) : "v"(x)); return r; }

// ---------------- prep: concat(enc, hid) -> bf16 A [2560][3072] ----------------
__global__ __launch_bounds__(256) void prep_x_kernel(const float* __restrict__ hs,
                                                     const float* __restrict__ ehs,
                                                     u16* __restrict__ A){
  int idx = blockIdx.x*256 + threadIdx.x;   // one float4 each; grid exact
  int v = idx*4;
  int m = v/3072, c = v - m*3072;
  int b = m/1280, s = m - b*1280;
  const float* src = (s < 256) ? (ehs + ((size_t)(b*256+s))*3072 + c)
                               : (hs  + ((size_t)(b*1024+(s-256)))*3072 + c);
  float4 f = *(const float4*)src;
  uint2 o; o.x = cvtpk_bf16(f.x, f.y); o.y = cvtpk_bf16(f.z, f.w);
  *(uint2*)(A + v) = o;
}

// ---------------- transpose W [K][N] f32 -> Wt [N][K] bf16 ----------------
__global__ __launch_bounds__(256) void transpose_w_kernel(const float* __restrict__ W,
                                                          u16* __restrict__ Wt,
                                                          int K, int N){
  __shared__ float t[64][36];
  int k0 = blockIdx.y*64, n0 = blockIdx.x*32;
  int tid = threadIdx.x;
  #pragma unroll
  for (int i=0;i<2;i++){
    int cell = i*256 + tid; int kl = cell>>3, nc = cell&7;
    *(float4*)&t[kl][nc*4] = *(const float4*)&W[(size_t)(k0+kl)*N + n0 + nc*4];
  }
  __syncthreads();
  #pragma unroll
  for (int i=0;i<2;i++){
    int chunk = i*256 + tid; int nl = chunk>>4, kc = chunk&15;
    float a = t[kc*4+0][nl], b2 = t[kc*4+1][nl], c2 = t[kc*4+2][nl], d2 = t[kc*4+3][nl];
    uint2 u; u.x = cvtpk_bf16(a, b2); u.y = cvtpk_bf16(c2, d2);
    *(uint2*)&Wt[(size_t)(n0+nl)*K + k0 + kc*4] = u;
  }
}

// ---------------- GEMM: C = A[M,K] * Bt[N,K]^T (+bias), m97 structure ----------------
// EPI 0: write bf16 to Cb (qkv).  EPI 1: write f32 to Cf with img/txt split.
template<int EPI>
__global__ __launch_bounds__(256) void gemm_bt_kernel(const u16* __restrict__ A,
                                                      const u16* __restrict__ Bt,
                                                      const float* __restrict__ bias,
                                                      u16* __restrict__ Cb, float* __restrict__ Cf,
                                                      int K, int N){
  __shared__ u16 As[2][4096];
  __shared__ u16 Bs[2][4096];
  int tid = threadIdx.x, wv = tid>>6, lane = tid&63;
  int l15 = lane & 15, l4 = lane >> 4;
  int m0 = blockIdx.y*128, n0 = blockIdx.x*128;
  int wr = wv>>1, wc = wv&1;

  f32x4 acc[4][4];
  #pragma unroll
  for (int i=0;i<4;i++)
    #pragma unroll
    for (int j=0;j<4;j++)
      #pragma unroll
      for (int r=0;r<4;r++) acc[i][j][r] = 0.f;

  const int NT = K >> 5;

  auto stage = [&](int buf, int kt){
    #pragma unroll
    for (int i=0;i<2;i++){
      int c = (wv*2+i)*64 + lane; int row = c>>2, kc = c&3;
      const u16* s = A + (size_t)(m0+row)*K + kt + kc*8;
      __builtin_amdgcn_global_load_lds((gptr_t)s, (lptr_t)(&As[buf][(wv*2+i)*512]), 16, 0, 0);
    }
    #pragma unroll
    for (int i=0;i<2;i++){
      int c = (wv*2+i)*64 + lane; int row = c>>2, kc = c&3;
      const u16* s = Bt + (size_t)(n0+row)*K + kt + kc*8;
      __builtin_amdgcn_global_load_lds((gptr_t)s, (lptr_t)(&Bs[buf][(wv*2+i)*512]), 16, 0, 0);
    }
  };

  stage(0, 0);
  __syncthreads();
  for (int t=0; t<NT; t++){
    int cur = t & 1;
    if (t+1 < NT) stage(cur^1, (t+1)*32);
    bf16x8 af[4], bfr[4];
    #pragma unroll
    for (int i=0;i<4;i++){
      af[i]  = *(const bf16x8*)&As[cur][(wr*64 + i*16 + l15)*32 + l4*8];
      bfr[i] = *(const bf16x8*)&Bs[cur][(wc*64 + i*16 + l15)*32 + l4*8];
    }
    #pragma unroll
    for (int i=0;i<4;i++)
      #pragma unroll
      for (int j=0;j<4;j++)
        acc[i][j] = __builtin_amdgcn_mfma_f32_16x16x32_bf16(af[i], bfr[j], acc[i][j], 0,0,0);
    __syncthreads();
  }

  #pragma unroll
  for (int i=0;i<4;i++){
    int row = m0 + wr*64 + i*16 + l4*4;
    #pragma unroll
    for (int j=0;j<4;j++){
      int col = n0 + wc*64 + j*16 + l15;
      float bv = bias[col];
      if (EPI == 0){
        #pragma unroll
        for (int r=0;r<4;r++)
          Cb[(size_t)(row+r)*N + col] = f2bf(acc[i][j][r] + bv);
      } else {
        #pragma unroll
        for (int r=0;r<4;r++){
          int rr = row + r;
          int bb = rr / 1280; int s = rr - bb*1280;
          float* dst = (s < 256) ? (Cf + 6291456 + ((size_t)(bb*256 + s))*3072)
                                 : (Cf + ((size_t)(bb*1024 + (s-256)))*3072);
          dst[col] = acc[i][j][r] + bv;
        }
      }
    }
  }
}

// ---------------- LayerNorm (no affine) + partial RoPE for Q,K ----------------
// one wave per (b,s,h); lane covers d and d+64 (RoPE pairing).
// Q gets scale = (1/sqrt(128)) * log2(e) folded in (softmax done in exp2).
__device__ __forceinline__ void ln_head(const u16* __restrict__ in, u16* __restrict__ out,
                                        const float* __restrict__ cosb, const float* __restrict__ sinb,
                                        int lane, int s, float scale){
  float x0 = bf2f(in[lane]), x1 = bf2f(in[64+lane]);
  float sum = x0 + x1;
  #pragma unroll
  for (int off=32; off>=1; off>>=1) sum += __shfl_xor(sum, off);
  float mean = sum * 0.0078125f;
  float d0 = x0-mean, d1 = x1-mean;
  float vs = d0*d0 + d1*d1;
  #pragma unroll
  for (int off=32; off>=1; off>>=1) vs += __shfl_xor(vs, off);
  float rstd = rsqrtf(vs*0.0078125f + 1e-5f);
  float y0 = d0*rstd, y1 = d1*rstd;
  if (s >= 256){
    int p = s - 256;
    float c0 = cosb[p*128 + lane], c1 = cosb[p*128 + 64 + lane];
    float s0 = sinb[p*128 + lane], s1 = sinb[p*128 + 64 + lane];
    float t0 = y0*c0 - y1*s0;   // d<64: x*cos - x[d+64]*sin
    float t1 = y1*c1 + y0*s1;   // d>=64: x*cos + x[d-64]*sin
    y0 = t0; y1 = t1;
  }
  out[lane]    = f2bf(y0*scale);
  out[64+lane] = f2bf(y1*scale);
}

__global__ __launch_bounds__(256) void ln_rope_kernel(const u16* __restrict__ qkv,
                                                      const float* __restrict__ cosb,
                                                      const float* __restrict__ sinb,
                                                      u16* __restrict__ Q, u16* __restrict__ Kd){
  int g = blockIdx.x*4 + (threadIdx.x>>6);
  int lane = threadIdx.x & 63;
  int h = g % 24; int m = g / 24;
  int b = m / 1280; int s = m - b*1280;
  const u16* base = qkv + (size_t)m*9216 + h*128;
  size_t ho = ((size_t)(b*24 + h)*1280 + s)*128;
  ln_head(base,        Q  + ho, cosb, sinb, lane, s, 0.12751512f); // (1/sqrt(128))*log2(e)
  ln_head(base + 3072, Kd + ho, cosb, sinb, lane, s, 1.0f);
}

// ---------------- V transpose: qkv v-region -> Vt [B*H][128][1280] bf16 ----------------
__global__ __launch_bounds__(256) void v_transpose_kernel(const u16* __restrict__ qkv,
                                                          u16* __restrict__ Vt){
  __shared__ u16 tl[16384]; // [s:128][chunk16:16][8] with chunk ^= (s>>3)&7
  int tid = threadIdx.x;
  int blk = blockIdx.x;
  int st = blk % 10; int bh = blk / 10; int b = bh/24, h = bh - b*24;
  #pragma unroll
  for (int i=0;i<8;i++){
    int idx = i*256 + tid; int s = idx>>4, dc = idx&15;
    int m = b*1280 + st*128 + s;
    bf16x8 v = *(const bf16x8*)(qkv + (size_t)m*9216 + 6144 + h*128 + dc*8);
    *(bf16x8*)(tl + (s*16 + (dc ^ ((s>>3)&7)))*8) = v;
  }
  __syncthreads();
  #pragma unroll
  for (int i=0;i<8;i++){
    int idx = i*256 + tid; int d = idx>>4, sc = idx&15;
    union { u16 t[8]; bf16x8 v; } tmp;
    #pragma unroll
    for (int j=0;j<8;j++){
      int s = sc*8 + j;
      tmp.t[j] = tl[(s*16 + ((d>>3) ^ ((s>>3)&7)))*8 + (d&7)];
    }
    *(bf16x8*)(Vt + ((size_t)bh*128 + d)*1280 + st*128 + sc*8) = tmp.v;
  }
}

// ---------------- flash attention: 4 waves x 32 q-rows, KVB=64 ----------------
// S^T = mfma(K,Q): lane-local softmax (col=q=lane&31).
// O^T = mfma(V^T, P^T): P^T built in-register via cvt_pk + permlane32_swap.
__global__ __launch_bounds__(256) void attn_kernel(const u16* __restrict__ Q,
                                                   const u16* __restrict__ Kg,
                                                   const u16* __restrict__ Vt,
                                                   u16* __restrict__ AO){
  __shared__ u16 smem[16384];      // 32KB: Ks 16KB | Vs 16KB ; reused as out-stage
  u16* Ks = smem;                  // [key:64][chunk16:16][8], chunk ^= key&7
  u16* Vs = smem + 8192;           // [d:128][kchunk:8][8],   kchunk ^= d&7
  int tid = threadIdx.x, wv = tid>>6, lane = tid&63;
  int l31 = lane & 31, hi = lane >> 5;
  int blk = blockIdx.x;
  int qt = blk % 10; int bh = blk / 10;
  int b = bh / 24; int h = bh - b*24;
  const u16* Qb = Q  + (size_t)bh*1280*128;
  const u16* Kb = Kg + (size_t)bh*1280*128;
  const u16* Vb = Vt + (size_t)bh*128*1280;
  int q0 = qt*128 + wv*32;

  bf16x8 qf[8];
  #pragma unroll
  for (int ds=0; ds<8; ds++)
    qf[ds] = *(const bf16x8*)(Qb + (size_t)(q0 + l31)*128 + ds*16 + hi*8);

  f32x16 o[4];
  #pragma unroll
  for (int dc=0; dc<4; dc++)
    #pragma unroll
    for (int r=0;r<16;r++) o[dc][r] = 0.f;
  float mrun = -1e30f, lrun = 0.f;

  for (int t=0; t<20; t++){
    int s0 = t*64;
    __syncthreads();   // all waves done reading previous tile
    #pragma unroll
    for (int i=0;i<4;i++){
      int c = (wv*4+i)*64 + lane; int key = c>>4, dc16 = c&15;
      const u16* src = Kb + (size_t)(s0+key)*128 + ((dc16 ^ (key&7))<<3);
      __builtin_amdgcn_global_load_lds((gptr_t)src, (lptr_t)(Ks + (wv*4+i)*512), 16, 0, 0);
    }
    #pragma unroll
    for (int i=0;i<4;i++){
      int c = (wv*4+i)*64 + lane; int d = c>>3, kc = c&7;
      const u16* src = Vb + (size_t)d*1280 + s0 + ((kc ^ (d&7))<<3);
      __builtin_amdgcn_global_load_lds((gptr_t)src, (lptr_t)(Vs + (wv*4+i)*512), 16, 0, 0);
    }
    __syncthreads();   // drains vmcnt -> tile staged

    f32x16 sacc0, sacc1;
    #pragma unroll
    for (int r=0;r<16;r++){ sacc0[r]=0.f; sacc1[r]=0.f; }
    #pragma unroll
    for (int ds=0; ds<8; ds++){
      int ch = ds*2 + hi;
      bf16x8 k0 = *(const bf16x8*)(Ks + (l31*16      + (ch ^ (l31 & 7)))*8);
      bf16x8 k1 = *(const bf16x8*)(Ks + ((32+l31)*16 + (ch ^ (l31 & 7)))*8);
      sacc0 = __builtin_amdgcn_mfma_f32_32x32x16_bf16(k0, qf[ds], sacc0, 0,0,0);
      sacc1 = __builtin_amdgcn_mfma_f32_32x32x16_bf16(k1, qf[ds], sacc1, 0,0,0);
    }
    // online softmax: lane q=l31 holds 32 of 64 key-scores, partner lane^32 the rest
    float mt = sacc0[0];
    #pragma unroll
    for (int r=1;r<16;r++) mt = fmaxf(mt, sacc0[r]);
    #pragma unroll
    for (int r=0;r<16;r++) mt = fmaxf(mt, sacc1[r]);
    mt = fmaxf(mt, __shfl_xor(mt, 32));
    float mnew = fmaxf(mrun, mt);
    float corr = fexp2(mrun - mnew);
    mrun = mnew;
    float p[32]; float ps = 0.f;
    #pragma unroll
    for (int r=0;r<16;r++){ p[r]    = fexp2(sacc0[r] - mnew); ps += p[r]; }
    #pragma unroll
    for (int r=0;r<16;r++){ p[16+r] = fexp2(sacc1[r] - mnew); ps += p[16+r]; }
    ps += __shfl_xor(ps, 32);
    lrun = lrun*corr + ps;
    #pragma unroll
    for (int dc=0; dc<4; dc++)
      #pragma unroll
      for (int r=0;r<16;r++) o[dc][r] *= corr;

    // P^T b-frags via cvt_pk + permlane32_swap (keys 16c+8hi+2w,+1 per word)
    bf16x8 pf[4];
    #pragma unroll
    for (int c=0;c<4;c++){
      const float* pp = p + (c>>1)*16 + (c&1)*8;
      unsigned x0 = cvtpk_bf16(pp[0], pp[1]);
      unsigned y0 = cvtpk_bf16(pp[4], pp[5]);
      unsigned x1 = cvtpk_bf16(pp[2], pp[3]);
      unsigned y1 = cvtpk_bf16(pp[6], pp[7]);
      asm volatile("v_permlane32_swap_b32 %0, %1" : "+v"(x0), "+v"(y0));
      asm volatile("v_permlane32_swap_b32 %0, %1" : "+v"(x1), "+v"(y1));
      union { unsigned u[4]; bf16x8 v; } wb;
      wb.u[0]=x0; wb.u[1]=x1; wb.u[2]=y0; wb.u[3]=y1;
      pf[c] = wb.v;
    }
    #pragma unroll
    for (int c=0;c<4;c++){
      #pragma unroll
      for (int dc=0;dc<4;dc++){
        int d = dc*32 + l31;
        bf16x8 vf = *(const bf16x8*)(Vs + (d*8 + ((2*c+hi) ^ (d&7)))*8);
        o[dc] = __builtin_amdgcn_mfma_f32_32x32x16_bf16(vf, pf[c], o[dc], 0,0,0);
      }
    }
  }

  // epilogue: normalize, LDS-transpose per wave, coalesced bf16 store
  float rl = 1.f / lrun;
  __syncthreads();                 // everyone done with Ks/Vs
  u16* ob = smem + wv*4096;        // 32 q x 128 d bf16, chunk16 ^= q&7
  #pragma unroll
  for (int dc=0; dc<4; dc++){
    #pragma unroll
    for (int rp=0; rp<8; rp++){
      int d = dc*32 + 2*(rp&1) + 8*(rp>>1) + 4*hi;
      unsigned u = cvtpk_bf16(o[dc][2*rp]*rl, o[dc][2*rp+1]*rl);
      int chs = (d>>3) ^ (l31 & 7);
      *(unsigned*)(ob + l31*128 + chs*8 + (d&7)) = u;
    }
  }
  __syncthreads();
  #pragma unroll
  for (int i=0;i<8;i++){
    int idx = i*64 + lane; int q = idx>>4, c8 = idx&15;
    bf16x8 vv = *(const bf16x8*)(ob + q*128 + ((c8 ^ (q&7))<<3));
    *(bf16x8*)(AO + (size_t)(b*1280 + q0 + q)*3072 + h*128 + c8*8) = vv;
  }
}

// ---------------- launch ----------------
extern "C" void kernel_launch(void* const* d_in, const int* in_sizes, int n_in,
                              void* d_out, int out_size, void* d_ws, size_t ws_size,
                              hipStream_t stream){
  (void)in_sizes; (void)n_in; (void)out_size; (void)ws_size;
  const float* hs   = (const float*)d_in[0];
  const float* ehs  = (const float*)d_in[1];
  const float* cosb = (const float*)d_in[2];
  const float* sinb = (const float*)d_in[3];
  const float* wqkv = (const float*)d_in[4];
  const float* bqkv = (const float*)d_in[5];
  const float* wout = (const float*)d_in[6];
  const float* bout = (const float*)d_in[7];
  char* w = (char*)d_ws;
  size_t o = 0;
  u16* Abf = (u16*)(w + o); o += 15728640ull;   // x concat bf16 [2560][3072]
  u16* WqT = (u16*)(w + o); o += 56623104ull;   // w_qkv^T bf16 [9216][3072]
  u16* WoT = (u16*)(w + o); o += 18874368ull;   // w_out^T bf16 [3072][3072]
  u16* qkv = (u16*)(w + o); o += 47185920ull;   // qkv bf16 [2560][9216]
  u16* Qd  = (u16*)(w + o); o += 15728640ull;   // Q [B*H][1280][128]
  u16* Kd  = (u16*)(w + o); o += 15728640ull;   // K [B*H][1280][128]
  u16* Vtd = (u16*)(w + o); o += 15728640ull;   // V^T [B*H][128][1280]
  u16* AO  = (u16*)(w + o);                     // attn out bf16 [2560][3072]
  float* out = (float*)d_out;

  prep_x_kernel<<<7680, 256, 0, stream>>>(hs, ehs, Abf);
  transpose_w_kernel<<<dim3(288,48), 256, 0, stream>>>(wqkv, WqT, 3072, 9216);
  transpose_w_kernel<<<dim3(96,48),  256, 0, stream>>>(wout, WoT, 3072, 3072);
  gemm_bt_kernel<0><<<dim3(72,20), 256, 0, stream>>>(Abf, WqT, bqkv, qkv, nullptr, 3072, 9216);
  ln_rope_kernel<<<15360, 256, 0, stream>>>(qkv, cosb, sinb, Qd, Kd);
  v_transpose_kernel<<<480, 256, 0, stream>>>(qkv, Vtd);
  attn_kernel<<<480, 256, 0, stream>>>(Qd, Kd, Vtd, AO);
  gemm_bt_kernel<1><<<dim3(24,20), 256, 0, stream>>>(AO, WoT, bout, nullptr, out, 3072, 3072);
}

// Round 3
// 572.046 us; speedup vs baseline: 1.0245x; 1.0245x over previous
//
#include <hip/hip_runtime.h>

typedef unsigned short u16;
typedef __attribute__((ext_vector_type(8))) short bf16x8;
typedef __attribute__((ext_vector_type(4))) float f32x4;
typedef __attribute__((ext_vector_type(16))) float f32x16;

typedef const __attribute__((address_space(1))) void* gptr_t;
typedef __attribute__((address_space(3))) void* lptr_t;

__device__ __forceinline__ unsigned cvtpk_bf16(float a, float b){
  unsigned r; asm("v_cvt_pk_bf16_f32 %0, %1, %2" : "=v"(r) : "v"(a), "v"(b)); return r;
}
__device__ __forceinline__ u16 f2bf(float x){ return (u16)cvtpk_bf16(x, x); }
__device__ __forceinline__ float bf2f(u16 u){ union{unsigned i; float f;} v; v.i = ((unsigned)u)<<16; return v.f; }
__device__ __forceinline__ float fexp2(float x){ float r; asm("v_exp_f32 %0, %1" : "=v"(r) : "v"(x)); return r; }

// ---------------- prep: concat(enc, hid) -> bf16 A [2560][3072] ----------------
__global__ __launch_bounds__(256) void prep_x_kernel(const float* __restrict__ hs,
                                                     const float* __restrict__ ehs,
                                                     u16* __restrict__ A){
  int idx = blockIdx.x*256 + threadIdx.x;
  int v = idx*4;
  int m = v/3072, c = v - m*3072;
  int b = m/1280, s = m - b*1280;
  const float* src = (s < 256) ? (ehs + ((size_t)(b*256+s))*3072 + c)
                               : (hs  + ((size_t)(b*1024+(s-256)))*3072 + c);
  float4 f = *(const float4*)src;
  uint2 o; o.x = cvtpk_bf16(f.x, f.y); o.y = cvtpk_bf16(f.z, f.w);
  *(uint2*)(A + v) = o;
}

// ---------------- transpose W [K][N] f32 -> Wt [N][K] bf16 ----------------
__global__ __launch_bounds__(256) void transpose_w_kernel(const float* __restrict__ W,
                                                          u16* __restrict__ Wt,
                                                          int K, int N){
  __shared__ float t[64][36];
  int k0 = blockIdx.y*64, n0 = blockIdx.x*32;
  int tid = threadIdx.x;
  #pragma unroll
  for (int i=0;i<2;i++){
    int cell = i*256 + tid; int kl = cell>>3, nc = cell&7;
    *(float4*)&t[kl][nc*4] = *(const float4*)&W[(size_t)(k0+kl)*N + n0 + nc*4];
  }
  __syncthreads();
  #pragma unroll
  for (int i=0;i<2;i++){
    int chunk = i*256 + tid; int nl = chunk>>4, kc = chunk&15;
    float a = t[kc*4+0][nl], b2 = t[kc*4+1][nl], c2 = t[kc*4+2][nl], d2 = t[kc*4+3][nl];
    uint2 u; u.x = cvtpk_bf16(a, b2); u.y = cvtpk_bf16(c2, d2);
    *(uint2*)&Wt[(size_t)(n0+nl)*K + k0 + kc*4] = u;
  }
}

// ---------------- QKV GEMM: 256x256 tile, BK=64 (2 k-halves), counted-vmcnt pipeline ----
// C[2560][9216] = A[2560][3072] * Bt[9216][3072]^T + bias, bf16 out.
// LDS: 4 independent (slot, khalf) pair-regions (A 16KB + B 16KB each) = 128KB.
// Group G = (tile G>>1, khalf G&1): reads pair(G), issues pair(G+3), vmcnt(8), barrier.
// Depth-3 lookahead proof: pair(G+3) region's previous reader = group G-1 (barrier-done);
// (G+3)&1 != G&1 so never the region being read this group.
__global__ __launch_bounds__(512) void gemm256_kernel(const u16* __restrict__ A,
                                                      const u16* __restrict__ Bt,
                                                      const float* __restrict__ bias,
                                                      u16* __restrict__ C){
  const int K = 3072, N = 9216;
  __shared__ __align__(16) u16 lds[2][2][2][8192]; // [slot][A/B][khalf][256r x 32k swz]
  int tid = threadIdx.x, wv = tid>>6, lane = tid&63;
  int wm = wv>>2, wn = wv&3;
  int l15 = lane&15, l4 = lane>>4;

  int bid = blockIdx.x;                 // 360 = 8 XCD * 45
  int wg = (bid&7)*45 + (bid>>3);
  int bm = wg/36, bn = wg%36;
  int m0 = bm*256, n0 = bn*256;

  // staging: thread covers rows {srow, srow+128}, swizzled chunk schn (8 elems)
  int srow = tid>>2;
  int schn = (tid&3) ^ ((tid>>3)&3);
  const u16* aSrc = A  + (size_t)(m0 + srow)*K + schn*8;
  const u16* bSrc = Bt + (size_t)(n0 + srow)*K + schn*8;
  u16* ldsF = &lds[0][0][0][0];

  auto stagePair = [&](int Gp){
    int s = (Gp>>1)&1, h = Gp&1;
    size_t ko = (size_t)Gp*32;
    u16* la = ldsF + s*32768 + h*8192 + wv*512;   // wave-uniform base
    u16* lb = la + 16384;
    const u16* a0 = aSrc + ko;
    const u16* b0 = bSrc + ko;
    __builtin_amdgcn_global_load_lds((gptr_t)a0,                 (lptr_t)la,        16,0,0);
    __builtin_amdgcn_global_load_lds((gptr_t)(a0+(size_t)128*K), (lptr_t)(la+4096), 16,0,0);
    __builtin_amdgcn_global_load_lds((gptr_t)b0,                 (lptr_t)lb,        16,0,0);
    __builtin_amdgcn_global_load_lds((gptr_t)(b0+(size_t)128*K), (lptr_t)(lb+4096), 16,0,0);
  };

  // MFMA frag offsets (u16 units within a half-region); cs invariant across frags
  int fcs = l4 ^ ((l15>>1)&3);
  int aoff = (wm*128 + l15)*32 + fcs*8;
  int boff = (wn*64  + l15)*32 + fcs*8;

  f32x4 acc[8][4];
  #pragma unroll
  for (int r=0;r<8;r++)
    #pragma unroll
    for (int c=0;c<4;c++)
      #pragma unroll
      for (int q=0;q<4;q++) acc[r][c][q] = 0.f;

  stagePair(0); stagePair(1); stagePair(2);
  asm volatile("s_waitcnt vmcnt(8)" ::: "memory");
  __builtin_amdgcn_s_barrier();

  auto group = [&](int G, bool issue){
    const u16* rA = ldsF + ((G>>1)&1)*32768 + (G&1)*8192;
    const u16* rB = rA + 16384;
    bf16x8 af[8], bfv[4];
    #pragma unroll
    for (int r=0;r<8;r++) af[r] = *(const bf16x8*)(rA + aoff + r*512);
    #pragma unroll
    for (int c=0;c<4;c++) bfv[c] = *(const bf16x8*)(rB + boff + c*512);
    if (issue) stagePair(G+3);
    __builtin_amdgcn_s_setprio(1);
    #pragma unroll
    for (int r=0;r<8;r++)
      #pragma unroll
      for (int c=0;c<4;c++)
        acc[r][c] = __builtin_amdgcn_mfma_f32_16x16x32_bf16(af[r], bfv[c], acc[r][c], 0,0,0);
    __builtin_amdgcn_s_setprio(0);
  };

  for (int G=0; G<93; ++G){
    group(G, true);
    asm volatile("s_waitcnt vmcnt(8)" ::: "memory");
    __builtin_amdgcn_s_barrier();
  }
  group(93,false); asm volatile("s_waitcnt vmcnt(4)" ::: "memory"); __builtin_amdgcn_s_barrier();
  group(94,false); asm volatile("s_waitcnt vmcnt(0)" ::: "memory"); __builtin_amdgcn_s_barrier();
  group(95,false);

  #pragma unroll
  for (int r=0;r<8;r++){
    int row = m0 + wm*128 + r*16 + l4*4;
    #pragma unroll
    for (int c=0;c<4;c++){
      int col = n0 + wn*64 + c*16 + l15;
      float bv = bias[col];
      #pragma unroll
      for (int q=0;q<4;q++)
        C[(size_t)(row+q)*N + col] = f2bf(acc[r][c][q] + bv);
    }
  }
}

// ---------------- out-proj GEMM: 128x128 m97 structure, f32 split epilogue ----------------
__global__ __launch_bounds__(256) void gemm_bt_kernel(const u16* __restrict__ A,
                                                      const u16* __restrict__ Bt,
                                                      const float* __restrict__ bias,
                                                      float* __restrict__ Cf,
                                                      int K, int N){
  __shared__ u16 As[2][4096];
  __shared__ u16 Bs[2][4096];
  int tid = threadIdx.x, wv = tid>>6, lane = tid&63;
  int l15 = lane & 15, l4 = lane >> 4;
  int m0 = blockIdx.y*128, n0 = blockIdx.x*128;
  int wr = wv>>1, wc = wv&1;

  f32x4 acc[4][4];
  #pragma unroll
  for (int i=0;i<4;i++)
    #pragma unroll
    for (int j=0;j<4;j++)
      #pragma unroll
      for (int r=0;r<4;r++) acc[i][j][r] = 0.f;

  const int NT = K >> 5;

  auto stage = [&](int buf, int kt){
    #pragma unroll
    for (int i=0;i<2;i++){
      int c = (wv*2+i)*64 + lane; int row = c>>2, kc = c&3;
      const u16* s = A + (size_t)(m0+row)*K + kt + kc*8;
      __builtin_amdgcn_global_load_lds((gptr_t)s, (lptr_t)(&As[buf][(wv*2+i)*512]), 16, 0, 0);
    }
    #pragma unroll
    for (int i=0;i<2;i++){
      int c = (wv*2+i)*64 + lane; int row = c>>2, kc = c&3;
      const u16* s = Bt + (size_t)(n0+row)*K + kt + kc*8;
      __builtin_amdgcn_global_load_lds((gptr_t)s, (lptr_t)(&Bs[buf][(wv*2+i)*512]), 16, 0, 0);
    }
  };

  stage(0, 0);
  __syncthreads();
  for (int t=0; t<NT; t++){
    int cur = t & 1;
    if (t+1 < NT) stage(cur^1, (t+1)*32);
    bf16x8 af[4], bfr[4];
    #pragma unroll
    for (int i=0;i<4;i++){
      af[i]  = *(const bf16x8*)&As[cur][(wr*64 + i*16 + l15)*32 + l4*8];
      bfr[i] = *(const bf16x8*)&Bs[cur][(wc*64 + i*16 + l15)*32 + l4*8];
    }
    #pragma unroll
    for (int i=0;i<4;i++)
      #pragma unroll
      for (int j=0;j<4;j++)
        acc[i][j] = __builtin_amdgcn_mfma_f32_16x16x32_bf16(af[i], bfr[j], acc[i][j], 0,0,0);
    __syncthreads();
  }

  #pragma unroll
  for (int i=0;i<4;i++){
    int row = m0 + wr*64 + i*16 + l4*4;
    #pragma unroll
    for (int j=0;j<4;j++){
      int col = n0 + wc*64 + j*16 + l15;
      float bv = bias[col];
      #pragma unroll
      for (int r=0;r<4;r++){
        int rr = row + r;
        int bb = rr / 1280; int s = rr - bb*1280;
        float* dst = (s < 256) ? (Cf + 6291456 + ((size_t)(bb*256 + s))*3072)
                               : (Cf + ((size_t)(bb*1024 + (s-256)))*3072);
        dst[col] = acc[i][j][r] + bv;
      }
    }
  }
}

// ---------------- LayerNorm (no affine) + partial RoPE for Q,K ----------------
__device__ __forceinline__ void ln_head(const u16* __restrict__ in, u16* __restrict__ out,
                                        const float* __restrict__ cosb, const float* __restrict__ sinb,
                                        int lane, int s, float scale){
  float x0 = bf2f(in[lane]), x1 = bf2f(in[64+lane]);
  float sum = x0 + x1;
  #pragma unroll
  for (int off=32; off>=1; off>>=1) sum += __shfl_xor(sum, off);
  float mean = sum * 0.0078125f;
  float d0 = x0-mean, d1 = x1-mean;
  float vs = d0*d0 + d1*d1;
  #pragma unroll
  for (int off=32; off>=1; off>>=1) vs += __shfl_xor(vs, off);
  float rstd = rsqrtf(vs*0.0078125f + 1e-5f);
  float y0 = d0*rstd, y1 = d1*rstd;
  if (s >= 256){
    int p = s - 256;
    float c0 = cosb[p*128 + lane], c1 = cosb[p*128 + 64 + lane];
    float s0 = sinb[p*128 + lane], s1 = sinb[p*128 + 64 + lane];
    float t0 = y0*c0 - y1*s0;
    float t1 = y1*c1 + y0*s1;
    y0 = t0; y1 = t1;
  }
  out[lane]    = f2bf(y0*scale);
  out[64+lane] = f2bf(y1*scale);
}

__global__ __launch_bounds__(256) void ln_rope_kernel(const u16* __restrict__ qkv,
                                                      const float* __restrict__ cosb,
                                                      const float* __restrict__ sinb,
                                                      u16* __restrict__ Q, u16* __restrict__ Kd){
  int g = blockIdx.x*4 + (threadIdx.x>>6);
  int lane = threadIdx.x & 63;
  int h = g % 24; int m = g / 24;
  int b = m / 1280; int s = m - b*1280;
  const u16* base = qkv + (size_t)m*9216 + h*128;
  size_t ho = ((size_t)(b*24 + h)*1280 + s)*128;
  ln_head(base,        Q  + ho, cosb, sinb, lane, s, 0.12751512f); // (1/sqrt(128))*log2(e)
  ln_head(base + 3072, Kd + ho, cosb, sinb, lane, s, 1.0f);
}

// ---------------- V transpose: qkv v-region -> Vt [B*H][128][1280] bf16 ----------------
__global__ __launch_bounds__(256) void v_transpose_kernel(const u16* __restrict__ qkv,
                                                          u16* __restrict__ Vt){
  __shared__ u16 tl[16384];
  int tid = threadIdx.x;
  int blk = blockIdx.x;
  int st = blk % 10; int bh = blk / 10; int b = bh/24, h = bh - b*24;
  #pragma unroll
  for (int i=0;i<8;i++){
    int idx = i*256 + tid; int s = idx>>4, dc = idx&15;
    int m = b*1280 + st*128 + s;
    bf16x8 v = *(const bf16x8*)(qkv + (size_t)m*9216 + 6144 + h*128 + dc*8);
    *(bf16x8*)(tl + (s*16 + (dc ^ ((s>>3)&7)))*8) = v;
  }
  __syncthreads();
  #pragma unroll
  for (int i=0;i<8;i++){
    int idx = i*256 + tid; int d = idx>>4, sc = idx&15;
    union { u16 t[8]; bf16x8 v; } tmp;
    #pragma unroll
    for (int j=0;j<8;j++){
      int s = sc*8 + j;
      tmp.t[j] = tl[(s*16 + ((d>>3) ^ ((s>>3)&7)))*8 + (d&7)];
    }
    *(bf16x8*)(Vt + ((size_t)bh*128 + d)*1280 + st*128 + sc*8) = tmp.v;
  }
}

// ---------------- flash attention: dbuf K/V, counted vmcnt(8), setprio ----------------
__global__ __launch_bounds__(256) void attn_kernel(const u16* __restrict__ Q,
                                                   const u16* __restrict__ Kg,
                                                   const u16* __restrict__ Vt,
                                                   u16* __restrict__ AO){
  __shared__ __align__(16) u16 smem[32768];  // 64KB: K0|K1|V0|V1 (8192 u16 each)
  int tid = threadIdx.x, wv = tid>>6, lane = tid&63;
  int l31 = lane & 31, hi = lane >> 5;
  int blk = blockIdx.x;
  int qt = blk % 10; int bh = blk / 10;
  int b = bh / 24; int h = bh - b*24;
  const u16* Qb = Q  + (size_t)bh*1280*128;
  const u16* Kb = Kg + (size_t)bh*1280*128;
  const u16* Vb = Vt + (size_t)bh*128*1280;
  int q0 = qt*128 + wv*32;

  bf16x8 qf[8];
  #pragma unroll
  for (int ds=0; ds<8; ds++)
    qf[ds] = *(const bf16x8*)(Qb + (size_t)(q0 + l31)*128 + ds*16 + hi*8);

  f32x16 o[4];
  #pragma unroll
  for (int dc=0; dc<4; dc++)
    #pragma unroll
    for (int r=0;r<16;r++) o[dc][r] = 0.f;
  float mrun = -1e30f, lrun = 0.f;

  auto stage = [&](int t){
    int s0 = t*64; int bu = t&1;
    u16* Ksb = smem + bu*8192;
    u16* Vsb = smem + 16384 + bu*8192;
    #pragma unroll
    for (int i=0;i<4;i++){
      int c = (wv*4+i)*64 + lane; int key = c>>4, dc16 = c&15;
      const u16* src = Kb + (size_t)(s0+key)*128 + ((dc16 ^ (key&7))<<3);
      __builtin_amdgcn_global_load_lds((gptr_t)src, (lptr_t)(Ksb + (wv*4+i)*512), 16, 0, 0);
    }
    #pragma unroll
    for (int i=0;i<4;i++){
      int c = (wv*4+i)*64 + lane; int d = c>>3, kc = c&7;
      const u16* src = Vb + (size_t)d*1280 + s0 + ((kc ^ (d&7))<<3);
      __builtin_amdgcn_global_load_lds((gptr_t)src, (lptr_t)(Vsb + (wv*4+i)*512), 16, 0, 0);
    }
  };

  auto compute = [&](int t){
    const u16* Ks = smem + (t&1)*8192;
    const u16* Vs = smem + 16384 + (t&1)*8192;
    f32x16 sacc0, sacc1;
    #pragma unroll
    for (int r=0;r<16;r++){ sacc0[r]=0.f; sacc1[r]=0.f; }
    __builtin_amdgcn_s_setprio(1);
    #pragma unroll
    for (int ds=0; ds<8; ds++){
      int ch = ds*2 + hi;
      bf16x8 k0 = *(const bf16x8*)(Ks + (l31*16      + (ch ^ (l31 & 7)))*8);
      bf16x8 k1 = *(const bf16x8*)(Ks + ((32+l31)*16 + (ch ^ (l31 & 7)))*8);
      sacc0 = __builtin_amdgcn_mfma_f32_32x32x16_bf16(k0, qf[ds], sacc0, 0,0,0);
      sacc1 = __builtin_amdgcn_mfma_f32_32x32x16_bf16(k1, qf[ds], sacc1, 0,0,0);
    }
    __builtin_amdgcn_s_setprio(0);
    float mt = sacc0[0];
    #pragma unroll
    for (int r=1;r<16;r++) mt = fmaxf(mt, sacc0[r]);
    #pragma unroll
    for (int r=0;r<16;r++) mt = fmaxf(mt, sacc1[r]);
    mt = fmaxf(mt, __shfl_xor(mt, 32));
    float mnew = fmaxf(mrun, mt);
    float corr = fexp2(mrun - mnew);
    mrun = mnew;
    float p[32]; float ps = 0.f;
    #pragma unroll
    for (int r=0;r<16;r++){ p[r]    = fexp2(sacc0[r] - mnew); ps += p[r]; }
    #pragma unroll
    for (int r=0;r<16;r++){ p[16+r] = fexp2(sacc1[r] - mnew); ps += p[16+r]; }
    ps += __shfl_xor(ps, 32);
    lrun = lrun*corr + ps;
    #pragma unroll
    for (int dc=0; dc<4; dc++)
      #pragma unroll
      for (int r=0;r<16;r++) o[dc][r] *= corr;

    bf16x8 pf[4];
    #pragma unroll
    for (int c=0;c<4;c++){
      const float* pp = p + (c>>1)*16 + (c&1)*8;
      unsigned x0 = cvtpk_bf16(pp[0], pp[1]);
      unsigned y0 = cvtpk_bf16(pp[4], pp[5]);
      unsigned x1 = cvtpk_bf16(pp[2], pp[3]);
      unsigned y1 = cvtpk_bf16(pp[6], pp[7]);
      asm volatile("v_permlane32_swap_b32 %0, %1" : "+v"(x0), "+v"(y0));
      asm volatile("v_permlane32_swap_b32 %0, %1" : "+v"(x1), "+v"(y1));
      union { unsigned u[4]; bf16x8 v; } wb;
      wb.u[0]=x0; wb.u[1]=x1; wb.u[2]=y0; wb.u[3]=y1;
      pf[c] = wb.v;
    }
    __builtin_amdgcn_s_setprio(1);
    #pragma unroll
    for (int c=0;c<4;c++){
      #pragma unroll
      for (int dc=0;dc<4;dc++){
        int d = dc*32 + l31;
        bf16x8 vf = *(const bf16x8*)(Vs + (d*8 + ((2*c+hi) ^ (d&7)))*8);
        o[dc] = __builtin_amdgcn_mfma_f32_32x32x16_bf16(vf, pf[c], o[dc], 0,0,0);
      }
    }
    __builtin_amdgcn_s_setprio(0);
  };

  stage(0); stage(1);
  for (int t=0; t<19; ++t){
    asm volatile("s_waitcnt vmcnt(8)" ::: "memory");  // tile t landed; t+1 in flight
    __builtin_amdgcn_s_barrier();
    compute(t);
    __builtin_amdgcn_s_barrier();                     // all reads of buf[t&1] done
    if (t <= 17) stage(t+2);
  }
  asm volatile("s_waitcnt vmcnt(0)" ::: "memory");
  __builtin_amdgcn_s_barrier();
  compute(19);

  // epilogue: normalize, LDS-transpose per wave, coalesced bf16 store
  float rl = 1.f / lrun;
  __syncthreads();
  u16* ob = smem + wv*4096;
  #pragma unroll
  for (int dc=0; dc<4; dc++){
    #pragma unroll
    for (int rp=0; rp<8; rp++){
      int d = dc*32 + 2*(rp&1) + 8*(rp>>1) + 4*hi;
      unsigned u = cvtpk_bf16(o[dc][2*rp]*rl, o[dc][2*rp+1]*rl);
      int chs = (d>>3) ^ (l31 & 7);
      *(unsigned*)(ob + l31*128 + chs*8 + (d&7)) = u;
    }
  }
  __syncthreads();
  #pragma unroll
  for (int i=0;i<8;i++){
    int idx = i*64 + lane; int q = idx>>4, c8 = idx&15;
    bf16x8 vv = *(const bf16x8*)(ob + q*128 + ((c8 ^ (q&7))<<3));
    *(bf16x8*)(AO + (size_t)(b*1280 + q0 + q)*3072 + h*128 + c8*8) = vv;
  }
}

// ---------------- launch ----------------
extern "C" void kernel_launch(void* const* d_in, const int* in_sizes, int n_in,
                              void* d_out, int out_size, void* d_ws, size_t ws_size,
                              hipStream_t stream){
  (void)in_sizes; (void)n_in; (void)out_size; (void)ws_size;
  const float* hs   = (const float*)d_in[0];
  const float* ehs  = (const float*)d_in[1];
  const float* cosb = (const float*)d_in[2];
  const float* sinb = (const float*)d_in[3];
  const float* wqkv = (const float*)d_in[4];
  const float* bqkv = (const float*)d_in[5];
  const float* wout = (const float*)d_in[6];
  const float* bout = (const float*)d_in[7];
  char* w = (char*)d_ws;
  size_t o = 0;
  u16* Abf = (u16*)(w + o); o += 15728640ull;   // x concat bf16 [2560][3072]
  u16* WqT = (u16*)(w + o); o += 56623104ull;   // w_qkv^T bf16 [9216][3072]
  u16* WoT = (u16*)(w + o); o += 18874368ull;   // w_out^T bf16 [3072][3072]
  u16* qkv = (u16*)(w + o); o += 47185920ull;   // qkv bf16 [2560][9216]
  u16* Qd  = (u16*)(w + o); o += 15728640ull;   // Q [B*H][1280][128]
  u16* Kd  = (u16*)(w + o); o += 15728640ull;   // K [B*H][1280][128]
  u16* Vtd = (u16*)(w + o); o += 15728640ull;   // V^T [B*H][128][1280]
  u16* AO  = (u16*)(w + o);                     // attn out bf16 [2560][3072]
  float* out = (float*)d_out;

  prep_x_kernel<<<7680, 256, 0, stream>>>(hs, ehs, Abf);
  transpose_w_kernel<<<dim3(288,48), 256, 0, stream>>>(wqkv, WqT, 3072, 9216);
  transpose_w_kernel<<<dim3(96,48),  256, 0, stream>>>(wout, WoT, 3072, 3072);
  gemm256_kernel<<<360, 512, 0, stream>>>(Abf, WqT, bqkv, qkv);
  ln_rope_kernel<<<15360, 256, 0, stream>>>(qkv, cosb, sinb, Qd, Kd);
  v_transpose_kernel<<<480, 256, 0, stream>>>(qkv, Vtd);
  attn_kernel<<<480, 256, 0, stream>>>(Qd, Kd, Vtd, AO);
  gemm_bt_kernel<<<dim3(24,20), 256, 0, stream>>>(AO, WoT, bout, out, 3072, 3072);
}

// Round 4
// 558.210 us; speedup vs baseline: 1.0499x; 1.0248x over previous
//
#include <hip/hip_runtime.h>

typedef unsigned short u16;
typedef __attribute__((ext_vector_type(8))) short bf16x8;
typedef __attribute__((ext_vector_type(4))) float f32x4;
typedef __attribute__((ext_vector_type(16))) float f32x16;

typedef const __attribute__((address_space(1))) void* gptr_t;
typedef __attribute__((address_space(3))) void* lptr_t;

__device__ __forceinline__ unsigned cvtpk_bf16(float a, float b){
  unsigned r; asm("v_cvt_pk_bf16_f32 %0, %1, %2" : "=v"(r) : "v"(a), "v"(b)); return r;
}
__device__ __forceinline__ u16 f2bf(float x){ return (u16)cvtpk_bf16(x, x); }
__device__ __forceinline__ float bf2f(u16 u){ union{unsigned i; float f;} v; v.i = ((unsigned)u)<<16; return v.f; }
__device__ __forceinline__ float fexp2(float x){ float r; asm("v_exp_f32 %0, %1" : "=v"(r) : "v"(x)); return r; }
__device__ __forceinline__ float vmax16(f32x16 v){
  float a0 = fmaxf(v[0],v[1]),  a1 = fmaxf(v[2],v[3]),  a2 = fmaxf(v[4],v[5]),  a3 = fmaxf(v[6],v[7]);
  float a4 = fmaxf(v[8],v[9]),  a5 = fmaxf(v[10],v[11]),a6 = fmaxf(v[12],v[13]),a7 = fmaxf(v[14],v[15]);
  float b0 = fmaxf(a0,a1), b1 = fmaxf(a2,a3), b2 = fmaxf(a4,a5), b3 = fmaxf(a6,a7);
  return fmaxf(fmaxf(b0,b1), fmaxf(b2,b3));
}

// ---------------- prep: concat(enc, hid) -> bf16 A [2560][3072] ----------------
__global__ __launch_bounds__(256) void prep_x_kernel(const float* __restrict__ hs,
                                                     const float* __restrict__ ehs,
                                                     u16* __restrict__ A){
  int idx = blockIdx.x*256 + threadIdx.x;
  int v = idx*4;
  int m = v/3072, c = v - m*3072;
  int b = m/1280, s = m - b*1280;
  const float* src = (s < 256) ? (ehs + ((size_t)(b*256+s))*3072 + c)
                               : (hs  + ((size_t)(b*1024+(s-256)))*3072 + c);
  float4 f = *(const float4*)src;
  uint2 o; o.x = cvtpk_bf16(f.x, f.y); o.y = cvtpk_bf16(f.z, f.w);
  *(uint2*)(A + v) = o;
}

// ---------------- transpose W [K][N] f32 -> Wt [N][K] bf16 ----------------
__global__ __launch_bounds__(256) void transpose_w_kernel(const float* __restrict__ W,
                                                          u16* __restrict__ Wt,
                                                          int K, int N){
  __shared__ float t[64][36];
  int k0 = blockIdx.y*64, n0 = blockIdx.x*32;
  int tid = threadIdx.x;
  #pragma unroll
  for (int i=0;i<2;i++){
    int cell = i*256 + tid; int kl = cell>>3, nc = cell&7;
    *(float4*)&t[kl][nc*4] = *(const float4*)&W[(size_t)(k0+kl)*N + n0 + nc*4];
  }
  __syncthreads();
  #pragma unroll
  for (int i=0;i<2;i++){
    int chunk = i*256 + tid; int nl = chunk>>4, kc = chunk&15;
    float a = t[kc*4+0][nl], b2 = t[kc*4+1][nl], c2 = t[kc*4+2][nl], d2 = t[kc*4+3][nl];
    uint2 u; u.x = cvtpk_bf16(a, b2); u.y = cvtpk_bf16(c2, d2);
    *(uint2*)&Wt[(size_t)(n0+nl)*K + k0 + kc*4] = u;
  }
}

// ---------------- QKV GEMM: 256x192 tile, BK=32 pairs, counted-vmcnt pipeline ----------
// grid 480 = 1.875 blocks/CU -> 94% makespan efficiency (vs 70% at 256x256/360).
// LDS: 4 pair-regions (A 16KB + B 12KB = 28KB) = 112KB. Pair G -> region G&3.
// Issue pair G+3 during group G; regions distinct mod 4; region (G+3)&3's last
// reader was group G-1 (behind barrier).
// Loads/pair/wave: w0-5: 2A+2B=4; w6-7: 2A. End-of-group wait: need pair G+1
// landed: w0-5 in-flight 12 -> vmcnt(4) (drains G+1,G+2; G+2 issued a full group
// ago, latency-covered); w6-7 in-flight 6 -> vmcnt(4) drains their G+1 ✓.
// Tail: after G=93 vmcnt(2) (w6-7: 4 in flight, drains pair94's A); after 94: 0.
__global__ __launch_bounds__(512) void gemm_qkv_kernel(const u16* __restrict__ A,
                                                       const u16* __restrict__ Bt,
                                                       const float* __restrict__ bias,
                                                       u16* __restrict__ C){
  const int K = 3072, N = 9216;
  __shared__ __align__(16) u16 lds[57344];   // 4 x 14336
  int tid = threadIdx.x, wv = tid>>6, lane = tid&63;
  int wm = wv>>2, wn = wv&3;
  int l15 = lane&15, l4 = lane>>4;

  int bid = blockIdx.x;                 // 480 = 8 XCD * 60
  int wg = (bid&7)*60 + (bid>>3);
  int bm = wg/48, bn = wg%48;
  int m0 = bm*256, n0 = bn*192;

  int rlane = lane>>2;
  int schn = (lane&3) ^ ((lane>>3)&3);  // LDS slot p holds global chunk p ^ ((row>>1)&3)
  const u16* aS = A + (size_t)(m0 + wv*32 + rlane)*K + schn*8;
  int brow = n0 + wv*32 + rlane; if (brow > 9215) brow = 9215;
  const u16* bS = Bt + (size_t)brow*K + schn*8;

  auto stagePair = [&](int G){
    u16* base = lds + (G&3)*14336;
    size_t ko = (size_t)G*32;
    #pragma unroll
    for (int j=0;j<2;j++)
      __builtin_amdgcn_global_load_lds((gptr_t)(aS + (size_t)j*16*K + ko),
                                       (lptr_t)(base + (wv*2+j)*512), 16,0,0);
    if (wv < 6){
      #pragma unroll
      for (int j=0;j<2;j++)
        __builtin_amdgcn_global_load_lds((gptr_t)(bS + (size_t)j*16*K + ko),
                                         (lptr_t)(base + 8192 + (wv*2+j)*512), 16,0,0);
    }
  };

  int fcs = l4 ^ ((l15>>1)&3);
  f32x4 acc[8][3];
  #pragma unroll
  for (int r=0;r<8;r++)
    #pragma unroll
    for (int c=0;c<3;c++)
      #pragma unroll
      for (int q=0;q<4;q++) acc[r][c][q] = 0.f;

  stagePair(0); stagePair(1); stagePair(2);
  asm volatile("s_waitcnt vmcnt(4)" ::: "memory");
  __builtin_amdgcn_s_barrier();

  auto group = [&](int G, bool issue){
    const u16* rA = lds + (G&3)*14336;
    const u16* rB = rA + 8192;
    bf16x8 af[8], bfv[3];
    #pragma unroll
    for (int r=0;r<8;r++) af[r] = *(const bf16x8*)(rA + (wm*128 + r*16 + l15)*32 + fcs*8);
    #pragma unroll
    for (int c=0;c<3;c++) bfv[c] = *(const bf16x8*)(rB + (wn*48 + c*16 + l15)*32 + fcs*8);
    if (issue) stagePair(G+3);
    __builtin_amdgcn_s_setprio(1);
    #pragma unroll
    for (int r=0;r<8;r++)
      #pragma unroll
      for (int c=0;c<3;c++)
        acc[r][c] = __builtin_amdgcn_mfma_f32_16x16x32_bf16(af[r], bfv[c], acc[r][c], 0,0,0);
    __builtin_amdgcn_s_setprio(0);
  };

  for (int G=0; G<93; ++G){
    group(G, true);
    asm volatile("s_waitcnt vmcnt(4)" ::: "memory");
    __builtin_amdgcn_s_barrier();
  }
  group(93,false); asm volatile("s_waitcnt vmcnt(2)" ::: "memory"); __builtin_amdgcn_s_barrier();
  group(94,false); asm volatile("s_waitcnt vmcnt(0)" ::: "memory"); __builtin_amdgcn_s_barrier();
  group(95,false);

  #pragma unroll
  for (int r=0;r<8;r++){
    int row = m0 + wm*128 + r*16 + l4*4;
    #pragma unroll
    for (int c=0;c<3;c++){
      int col = n0 + wn*48 + c*16 + l15;
      float bv = bias[col];
      #pragma unroll
      for (int q=0;q<4;q++)
        C[(size_t)(row+q)*N + col] = f2bf(acc[r][c][q] + bv);
    }
  }
}

// ---------------- out-proj GEMM: 128x128 m97 structure, f32 split epilogue ----------------
__global__ __launch_bounds__(256) void gemm_bt_kernel(const u16* __restrict__ A,
                                                      const u16* __restrict__ Bt,
                                                      const float* __restrict__ bias,
                                                      float* __restrict__ Cf,
                                                      int K, int N){
  __shared__ u16 As[2][4096];
  __shared__ u16 Bs[2][4096];
  int tid = threadIdx.x, wv = tid>>6, lane = tid&63;
  int l15 = lane & 15, l4 = lane >> 4;
  int m0 = blockIdx.y*128, n0 = blockIdx.x*128;
  int wr = wv>>1, wc = wv&1;

  f32x4 acc[4][4];
  #pragma unroll
  for (int i=0;i<4;i++)
    #pragma unroll
    for (int j=0;j<4;j++)
      #pragma unroll
      for (int r=0;r<4;r++) acc[i][j][r] = 0.f;

  const int NT = K >> 5;

  auto stage = [&](int buf, int kt){
    #pragma unroll
    for (int i=0;i<2;i++){
      int c = (wv*2+i)*64 + lane; int row = c>>2, kc = c&3;
      const u16* s = A + (size_t)(m0+row)*K + kt + kc*8;
      __builtin_amdgcn_global_load_lds((gptr_t)s, (lptr_t)(&As[buf][(wv*2+i)*512]), 16, 0, 0);
    }
    #pragma unroll
    for (int i=0;i<2;i++){
      int c = (wv*2+i)*64 + lane; int row = c>>2, kc = c&3;
      const u16* s = Bt + (size_t)(n0+row)*K + kt + kc*8;
      __builtin_amdgcn_global_load_lds((gptr_t)s, (lptr_t)(&Bs[buf][(wv*2+i)*512]), 16, 0, 0);
    }
  };

  stage(0, 0);
  __syncthreads();
  for (int t=0; t<NT; t++){
    int cur = t & 1;
    if (t+1 < NT) stage(cur^1, (t+1)*32);
    bf16x8 af[4], bfr[4];
    #pragma unroll
    for (int i=0;i<4;i++){
      af[i]  = *(const bf16x8*)&As[cur][(wr*64 + i*16 + l15)*32 + l4*8];
      bfr[i] = *(const bf16x8*)&Bs[cur][(wc*64 + i*16 + l15)*32 + l4*8];
    }
    #pragma unroll
    for (int i=0;i<4;i++)
      #pragma unroll
      for (int j=0;j<4;j++)
        acc[i][j] = __builtin_amdgcn_mfma_f32_16x16x32_bf16(af[i], bfr[j], acc[i][j], 0,0,0);
    __syncthreads();
  }

  #pragma unroll
  for (int i=0;i<4;i++){
    int row = m0 + wr*64 + i*16 + l4*4;
    #pragma unroll
    for (int j=0;j<4;j++){
      int col = n0 + wc*64 + j*16 + l15;
      float bv = bias[col];
      #pragma unroll
      for (int r=0;r<4;r++){
        int rr = row + r;
        int bb = rr / 1280; int s = rr - bb*1280;
        float* dst = (s < 256) ? (Cf + 6291456 + ((size_t)(bb*256 + s))*3072)
                               : (Cf + ((size_t)(bb*1024 + (s-256)))*3072);
        dst[col] = acc[i][j][r] + bv;
      }
    }
  }
}

// ---------------- LayerNorm (no affine) + partial RoPE for Q,K ----------------
__device__ __forceinline__ void ln_head(const u16* __restrict__ in, u16* __restrict__ out,
                                        const float* __restrict__ cosb, const float* __restrict__ sinb,
                                        int lane, int s, float scale){
  float x0 = bf2f(in[lane]), x1 = bf2f(in[64+lane]);
  float sum = x0 + x1;
  #pragma unroll
  for (int off=32; off>=1; off>>=1) sum += __shfl_xor(sum, off);
  float mean = sum * 0.0078125f;
  float d0 = x0-mean, d1 = x1-mean;
  float vs = d0*d0 + d1*d1;
  #pragma unroll
  for (int off=32; off>=1; off>>=1) vs += __shfl_xor(vs, off);
  float rstd = rsqrtf(vs*0.0078125f + 1e-5f);
  float y0 = d0*rstd, y1 = d1*rstd;
  if (s >= 256){
    int p = s - 256;
    float c0 = cosb[p*128 + lane], c1 = cosb[p*128 + 64 + lane];
    float s0 = sinb[p*128 + lane], s1 = sinb[p*128 + 64 + lane];
    float t0 = y0*c0 - y1*s0;
    float t1 = y1*c1 + y0*s1;
    y0 = t0; y1 = t1;
  }
  out[lane]    = f2bf(y0*scale);
  out[64+lane] = f2bf(y1*scale);
}

__global__ __launch_bounds__(256) void ln_rope_kernel(const u16* __restrict__ qkv,
                                                      const float* __restrict__ cosb,
                                                      const float* __restrict__ sinb,
                                                      u16* __restrict__ Q, u16* __restrict__ Kd){
  int g = blockIdx.x*4 + (threadIdx.x>>6);
  int lane = threadIdx.x & 63;
  int h = g % 24; int m = g / 24;
  int b = m / 1280; int s = m - b*1280;
  const u16* base = qkv + (size_t)m*9216 + h*128;
  size_t ho = ((size_t)(b*24 + h)*1280 + s)*128;
  ln_head(base,        Q  + ho, cosb, sinb, lane, s, 0.12751512f); // (1/sqrt(128))*log2(e)
  ln_head(base + 3072, Kd + ho, cosb, sinb, lane, s, 1.0f);
}

// ---------------- V transpose: qkv v-region -> Vt [B*H][128][1280] bf16 ----------------
__global__ __launch_bounds__(256) void v_transpose_kernel(const u16* __restrict__ qkv,
                                                          u16* __restrict__ Vt){
  __shared__ u16 tl[16384];
  int tid = threadIdx.x;
  int blk = blockIdx.x;
  int st = blk % 10; int bh = blk / 10; int b = bh/24, h = bh - b*24;
  #pragma unroll
  for (int i=0;i<8;i++){
    int idx = i*256 + tid; int s = idx>>4, dc = idx&15;
    int m = b*1280 + st*128 + s;
    bf16x8 v = *(const bf16x8*)(qkv + (size_t)m*9216 + 6144 + h*128 + dc*8);
    *(bf16x8*)(tl + (s*16 + (dc ^ ((s>>3)&7)))*8) = v;
  }
  __syncthreads();
  #pragma unroll
  for (int i=0;i<8;i++){
    int idx = i*256 + tid; int d = idx>>4, sc = idx&15;
    union { u16 t[8]; bf16x8 v; } tmp;
    #pragma unroll
    for (int j=0;j<8;j++){
      int s = sc*8 + j;
      tmp.t[j] = tl[(s*16 + ((d>>3) ^ ((s>>3)&7)))*8 + (d&7)];
    }
    *(bf16x8*)(Vt + ((size_t)bh*128 + d)*1280 + st*128 + sc*8) = tmp.v;
  }
}

// ---------------- flash attention: dbuf K/V, counted vmcnt(8), 4 QK chains, defer-rescale ----
__global__ __launch_bounds__(256) void attn_kernel(const u16* __restrict__ Q,
                                                   const u16* __restrict__ Kg,
                                                   const u16* __restrict__ Vt,
                                                   u16* __restrict__ AO){
  __shared__ __align__(16) u16 smem[32768];  // 64KB: K0|K1|V0|V1 (8192 u16 each)
  int tid = threadIdx.x, wv = tid>>6, lane = tid&63;
  int l31 = lane & 31, hi = lane >> 5;
  int blk = blockIdx.x;
  int qt = blk % 10; int bh = blk / 10;
  int b = bh / 24; int h = bh - b*24;
  const u16* Qb = Q  + (size_t)bh*1280*128;
  const u16* Kb = Kg + (size_t)bh*1280*128;
  const u16* Vb = Vt + (size_t)bh*128*1280;
  int q0 = qt*128 + wv*32;

  bf16x8 qf[8];
  #pragma unroll
  for (int ds=0; ds<8; ds++)
    qf[ds] = *(const bf16x8*)(Qb + (size_t)(q0 + l31)*128 + ds*16 + hi*8);

  f32x16 o[4];
  #pragma unroll
  for (int dc=0; dc<4; dc++)
    #pragma unroll
    for (int r=0;r<16;r++) o[dc][r] = 0.f;
  float mrun = -1e30f, lrun = 0.f;

  auto stage = [&](int t){
    int s0 = t*64; int bu = t&1;
    u16* Ksb = smem + bu*8192;
    u16* Vsb = smem + 16384 + bu*8192;
    #pragma unroll
    for (int i=0;i<4;i++){
      int c = (wv*4+i)*64 + lane; int key = c>>4, dc16 = c&15;
      const u16* src = Kb + (size_t)(s0+key)*128 + ((dc16 ^ (key&7))<<3);
      __builtin_amdgcn_global_load_lds((gptr_t)src, (lptr_t)(Ksb + (wv*4+i)*512), 16, 0, 0);
    }
    #pragma unroll
    for (int i=0;i<4;i++){
      int c = (wv*4+i)*64 + lane; int d = c>>3, kc = c&7;
      const u16* src = Vb + (size_t)d*1280 + s0 + ((kc ^ (d&7))<<3);
      __builtin_amdgcn_global_load_lds((gptr_t)src, (lptr_t)(Vsb + (wv*4+i)*512), 16, 0, 0);
    }
  };

  auto compute = [&](int t){
    const u16* Ks = smem + (t&1)*8192;
    const u16* Vs = smem + 16384 + (t&1)*8192;
    f32x16 sA, sB, sC, sD;
    #pragma unroll
    for (int r=0;r<16;r++){ sA[r]=0.f; sB[r]=0.f; sC[r]=0.f; sD[r]=0.f; }
    __builtin_amdgcn_s_setprio(1);
    #pragma unroll
    for (int dp=0; dp<4; dp++){            // 4 independent accumulation chains
      int dsE = 2*dp, dsO = 2*dp+1;
      int chE = dsE*2 + hi, chO = dsO*2 + hi;
      bf16x8 k0E = *(const bf16x8*)(Ks + (l31*16      + (chE ^ (l31 & 7)))*8);
      bf16x8 k1E = *(const bf16x8*)(Ks + ((32+l31)*16 + (chE ^ (l31 & 7)))*8);
      bf16x8 k0O = *(const bf16x8*)(Ks + (l31*16      + (chO ^ (l31 & 7)))*8);
      bf16x8 k1O = *(const bf16x8*)(Ks + ((32+l31)*16 + (chO ^ (l31 & 7)))*8);
      sA = __builtin_amdgcn_mfma_f32_32x32x16_bf16(k0E, qf[dsE], sA, 0,0,0);
      sC = __builtin_amdgcn_mfma_f32_32x32x16_bf16(k1E, qf[dsE], sC, 0,0,0);
      sB = __builtin_amdgcn_mfma_f32_32x32x16_bf16(k0O, qf[dsO], sB, 0,0,0);
      sD = __builtin_amdgcn_mfma_f32_32x32x16_bf16(k1O, qf[dsO], sD, 0,0,0);
    }
    __builtin_amdgcn_s_setprio(0);
    f32x16 sacc0, sacc1;
    #pragma unroll
    for (int r=0;r<16;r++){ sacc0[r] = sA[r]+sB[r]; sacc1[r] = sC[r]+sD[r]; }

    float mt = fmaxf(vmax16(sacc0), vmax16(sacc1));
    mt = fmaxf(mt, __shfl_xor(mt, 32));
    // defer-rescale (T13): skip o-rescale when tile max close to running max
    int noresc = __all(mt <= mrun + 11.5f);   // 8*log2(e)
    float mnew, corr;
    if (noresc){ mnew = mrun; corr = 1.f; }
    else       { mnew = fmaxf(mrun, mt); corr = fexp2(mrun - mnew); }
    mrun = mnew;
    float p[32];
    float ps0=0.f, ps1=0.f, ps2=0.f, ps3=0.f;
    #pragma unroll
    for (int r=0;r<8;r++){ p[r]    = fexp2(sacc0[r]   - mnew); ps0 += p[r]; }
    #pragma unroll
    for (int r=0;r<8;r++){ p[8+r]  = fexp2(sacc0[8+r] - mnew); ps1 += p[8+r]; }
    #pragma unroll
    for (int r=0;r<8;r++){ p[16+r] = fexp2(sacc1[r]   - mnew); ps2 += p[16+r]; }
    #pragma unroll
    for (int r=0;r<8;r++){ p[24+r] = fexp2(sacc1[8+r] - mnew); ps3 += p[24+r]; }
    float ps = (ps0+ps1) + (ps2+ps3);
    ps += __shfl_xor(ps, 32);
    lrun = lrun*corr + ps;
    if (!noresc){
      #pragma unroll
      for (int dc=0; dc<4; dc++)
        #pragma unroll
        for (int r=0;r<16;r++) o[dc][r] *= corr;
    }

    bf16x8 pf[4];
    #pragma unroll
    for (int c=0;c<4;c++){
      const float* pp = p + (c>>1)*16 + (c&1)*8;
      unsigned x0 = cvtpk_bf16(pp[0], pp[1]);
      unsigned y0 = cvtpk_bf16(pp[4], pp[5]);
      unsigned x1 = cvtpk_bf16(pp[2], pp[3]);
      unsigned y1 = cvtpk_bf16(pp[6], pp[7]);
      asm volatile("v_permlane32_swap_b32 %0, %1" : "+v"(x0), "+v"(y0));
      asm volatile("v_permlane32_swap_b32 %0, %1" : "+v"(x1), "+v"(y1));
      union { unsigned u[4]; bf16x8 v; } wb;
      wb.u[0]=x0; wb.u[1]=x1; wb.u[2]=y0; wb.u[3]=y1;
      pf[c] = wb.v;
    }
    __builtin_amdgcn_s_setprio(1);
    #pragma unroll
    for (int c=0;c<4;c++){
      #pragma unroll
      for (int dc=0;dc<4;dc++){
        int d = dc*32 + l31;
        bf16x8 vf = *(const bf16x8*)(Vs + (d*8 + ((2*c+hi) ^ (d&7)))*8);
        o[dc] = __builtin_amdgcn_mfma_f32_32x32x16_bf16(vf, pf[c], o[dc], 0,0,0);
      }
    }
    __builtin_amdgcn_s_setprio(0);
  };

  stage(0); stage(1);
  for (int t=0; t<19; ++t){
    asm volatile("s_waitcnt vmcnt(8)" ::: "memory");  // tile t landed; t+1 in flight
    __builtin_amdgcn_s_barrier();
    compute(t);
    __builtin_amdgcn_s_barrier();                     // all reads of buf[t&1] done
    if (t <= 17) stage(t+2);
  }
  asm volatile("s_waitcnt vmcnt(0)" ::: "memory");
  __builtin_amdgcn_s_barrier();
  compute(19);

  // epilogue: normalize, LDS-transpose per wave, coalesced bf16 store
  float rl = 1.f / lrun;
  __syncthreads();
  u16* ob = smem + wv*4096;
  #pragma unroll
  for (int dc=0; dc<4; dc++){
    #pragma unroll
    for (int rp=0; rp<8; rp++){
      int d = dc*32 + 2*(rp&1) + 8*(rp>>1) + 4*hi;
      unsigned u = cvtpk_bf16(o[dc][2*rp]*rl, o[dc][2*rp+1]*rl);
      int chs = (d>>3) ^ (l31 & 7);
      *(unsigned*)(ob + l31*128 + chs*8 + (d&7)) = u;
    }
  }
  __syncthreads();
  #pragma unroll
  for (int i=0;i<8;i++){
    int idx = i*64 + lane; int q = idx>>4, c8 = idx&15;
    bf16x8 vv = *(const bf16x8*)(ob + q*128 + ((c8 ^ (q&7))<<3));
    *(bf16x8*)(AO + (size_t)(b*1280 + q0 + q)*3072 + h*128 + c8*8) = vv;
  }
}

// ---------------- launch ----------------
extern "C" void kernel_launch(void* const* d_in, const int* in_sizes, int n_in,
                              void* d_out, int out_size, void* d_ws, size_t ws_size,
                              hipStream_t stream){
  (void)in_sizes; (void)n_in; (void)out_size; (void)ws_size;
  const float* hs   = (const float*)d_in[0];
  const float* ehs  = (const float*)d_in[1];
  const float* cosb = (const float*)d_in[2];
  const float* sinb = (const float*)d_in[3];
  const float* wqkv = (const float*)d_in[4];
  const float* bqkv = (const float*)d_in[5];
  const float* wout = (const float*)d_in[6];
  const float* bout = (const float*)d_in[7];
  char* w = (char*)d_ws;
  size_t o = 0;
  u16* Abf = (u16*)(w + o); o += 15728640ull;   // x concat bf16 [2560][3072]
  u16* WqT = (u16*)(w + o); o += 56623104ull;   // w_qkv^T bf16 [9216][3072]
  u16* WoT = (u16*)(w + o); o += 18874368ull;   // w_out^T bf16 [3072][3072]
  u16* qkv = (u16*)(w + o); o += 47185920ull;   // qkv bf16 [2560][9216]
  u16* Qd  = (u16*)(w + o); o += 15728640ull;   // Q [B*H][1280][128]
  u16* Kd  = (u16*)(w + o); o += 15728640ull;   // K [B*H][1280][128]
  u16* Vtd = (u16*)(w + o); o += 15728640ull;   // V^T [B*H][128][1280]
  u16* AO  = (u16*)(w + o);                     // attn out bf16 [2560][3072]
  float* out = (float*)d_out;

  prep_x_kernel<<<7680, 256, 0, stream>>>(hs, ehs, Abf);
  transpose_w_kernel<<<dim3(288,48), 256, 0, stream>>>(wqkv, WqT, 3072, 9216);
  transpose_w_kernel<<<dim3(96,48),  256, 0, stream>>>(wout, WoT, 3072, 3072);
  gemm_qkv_kernel<<<480, 512, 0, stream>>>(Abf, WqT, bqkv, qkv);
  ln_rope_kernel<<<15360, 256, 0, stream>>>(qkv, cosb, sinb, Qd, Kd);
  v_transpose_kernel<<<480, 256, 0, stream>>>(qkv, Vtd);
  attn_kernel<<<480, 256, 0, stream>>>(Qd, Kd, Vtd, AO);
  gemm_bt_kernel<<<dim3(24,20), 256, 0, stream>>>(AO, WoT, bout, out, 3072, 3072);
}

// Round 6
// 519.417 us; speedup vs baseline: 1.1283x; 1.0747x over previous
//
#include <hip/hip_runtime.h>

typedef unsigned short u16;
typedef __attribute__((ext_vector_type(8))) short bf16x8;
typedef __attribute__((ext_vector_type(4))) float f32x4;
typedef __attribute__((ext_vector_type(16))) float f32x16;

typedef const __attribute__((address_space(1))) void* gptr_t;
typedef __attribute__((address_space(3))) void* lptr_t;

__device__ __forceinline__ unsigned cvtpk_bf16(float a, float b){
  unsigned r; asm("v_cvt_pk_bf16_f32 %0, %1, %2" : "=v"(r) : "v"(a), "v"(b)); return r;
}
__device__ __forceinline__ u16 f2bf(float x){ return (u16)cvtpk_bf16(x, x); }
__device__ __forceinline__ float bf2f(u16 u){ union{unsigned i; float f;} v; v.i = ((unsigned)u)<<16; return v.f; }
__device__ __forceinline__ float fexp2(float x){ float r; asm("v_exp_f32 %0, %1" : "=v"(r) : "v"(x)); return r; }
__device__ __forceinline__ float vmax16(f32x16 v){
  float a0 = fmaxf(v[0],v[1]),  a1 = fmaxf(v[2],v[3]),  a2 = fmaxf(v[4],v[5]),  a3 = fmaxf(v[6],v[7]);
  float a4 = fmaxf(v[8],v[9]),  a5 = fmaxf(v[10],v[11]),a6 = fmaxf(v[12],v[13]),a7 = fmaxf(v[14],v[15]);
  float b0 = fmaxf(a0,a1), b1 = fmaxf(a2,a3), b2 = fmaxf(a4,a5), b3 = fmaxf(a6,a7);
  return fmaxf(fmaxf(b0,b1), fmaxf(b2,b3));
}

// ---------------- prep: concat(enc, hid) -> bf16 A [2560][3072] ----------------
__global__ __launch_bounds__(256) void prep_x_kernel(const float* __restrict__ hs,
                                                     const float* __restrict__ ehs,
                                                     u16* __restrict__ A){
  int idx = blockIdx.x*256 + threadIdx.x;
  int v = idx*4;
  int m = v/3072, c = v - m*3072;
  int b = m/1280, s = m - b*1280;
  const float* src = (s < 256) ? (ehs + ((size_t)(b*256+s))*3072 + c)
                               : (hs  + ((size_t)(b*1024+(s-256)))*3072 + c);
  float4 f = *(const float4*)src;
  uint2 o; o.x = cvtpk_bf16(f.x, f.y); o.y = cvtpk_bf16(f.z, f.w);
  *(uint2*)(A + v) = o;
}

// ---------------- transpose W [K][N] f32 -> Wt [N][K] bf16 ----------------
__global__ __launch_bounds__(256) void transpose_w_kernel(const float* __restrict__ W,
                                                          u16* __restrict__ Wt,
                                                          int K, int N){
  __shared__ float t[64][36];
  int k0 = blockIdx.y*64, n0 = blockIdx.x*32;
  int tid = threadIdx.x;
  #pragma unroll
  for (int i=0;i<2;i++){
    int cell = i*256 + tid; int kl = cell>>3, nc = cell&7;
    *(float4*)&t[kl][nc*4] = *(const float4*)&W[(size_t)(k0+kl)*N + n0 + nc*4];
  }
  __syncthreads();
  #pragma unroll
  for (int i=0;i<2;i++){
    int chunk = i*256 + tid; int nl = chunk>>4, kc = chunk&15;
    float a = t[kc*4+0][nl], b2 = t[kc*4+1][nl], c2 = t[kc*4+2][nl], d2 = t[kc*4+3][nl];
    uint2 u; u.x = cvtpk_bf16(a, b2); u.y = cvtpk_bf16(c2, d2);
    *(uint2*)&Wt[(size_t)(n0+nl)*K + k0 + kc*4] = u;
  }
}

// ---------------- QKV GEMM: 256x192 tile, BK=32 pairs, counted-vmcnt pipeline ----------
__global__ __launch_bounds__(512) void gemm_qkv_kernel(const u16* __restrict__ A,
                                                       const u16* __restrict__ Bt,
                                                       const float* __restrict__ bias,
                                                       u16* __restrict__ C){
  const int K = 3072, N = 9216;
  __shared__ __align__(16) u16 lds[57344];   // 4 x 14336
  int tid = threadIdx.x, wv = tid>>6, lane = tid&63;
  int wm = wv>>2, wn = wv&3;
  int l15 = lane&15, l4 = lane>>4;

  int bid = blockIdx.x;                 // 480 = 8 XCD * 60
  int wg = (bid&7)*60 + (bid>>3);
  int bm = wg/48, bn = wg%48;
  int m0 = bm*256, n0 = bn*192;

  int rlane = lane>>2;
  int schn = (lane&3) ^ ((lane>>3)&3);
  const u16* aS = A + (size_t)(m0 + wv*32 + rlane)*K + schn*8;
  int brow = n0 + wv*32 + rlane; if (brow > 9215) brow = 9215;
  const u16* bS = Bt + (size_t)brow*K + schn*8;

  auto stagePair = [&](int G){
    u16* base = lds + (G&3)*14336;
    size_t ko = (size_t)G*32;
    #pragma unroll
    for (int j=0;j<2;j++)
      __builtin_amdgcn_global_load_lds((gptr_t)(aS + (size_t)j*16*K + ko),
                                       (lptr_t)(base + (wv*2+j)*512), 16,0,0);
    if (wv < 6){
      #pragma unroll
      for (int j=0;j<2;j++)
        __builtin_amdgcn_global_load_lds((gptr_t)(bS + (size_t)j*16*K + ko),
                                         (lptr_t)(base + 8192 + (wv*2+j)*512), 16,0,0);
    }
  };

  int fcs = l4 ^ ((l15>>1)&3);
  f32x4 acc[8][3];
  #pragma unroll
  for (int r=0;r<8;r++)
    #pragma unroll
    for (int c=0;c<3;c++)
      #pragma unroll
      for (int q=0;q<4;q++) acc[r][c][q] = 0.f;

  stagePair(0); stagePair(1); stagePair(2);
  asm volatile("s_waitcnt vmcnt(4)" ::: "memory");
  __builtin_amdgcn_s_barrier();

  auto group = [&](int G, bool issue){
    const u16* rA = lds + (G&3)*14336;
    const u16* rB = rA + 8192;
    bf16x8 af[8], bfv[3];
    #pragma unroll
    for (int r=0;r<8;r++) af[r] = *(const bf16x8*)(rA + (wm*128 + r*16 + l15)*32 + fcs*8);
    #pragma unroll
    for (int c=0;c<3;c++) bfv[c] = *(const bf16x8*)(rB + (wn*48 + c*16 + l15)*32 + fcs*8);
    if (issue) stagePair(G+3);
    __builtin_amdgcn_s_setprio(1);
    #pragma unroll
    for (int r=0;r<8;r++)
      #pragma unroll
      for (int c=0;c<3;c++)
        acc[r][c] = __builtin_amdgcn_mfma_f32_16x16x32_bf16(af[r], bfv[c], acc[r][c], 0,0,0);
    __builtin_amdgcn_s_setprio(0);
  };

  for (int G=0; G<93; ++G){
    group(G, true);
    asm volatile("s_waitcnt vmcnt(4)" ::: "memory");
    __builtin_amdgcn_s_barrier();
  }
  group(93,false); asm volatile("s_waitcnt vmcnt(2)" ::: "memory"); __builtin_amdgcn_s_barrier();
  group(94,false); asm volatile("s_waitcnt vmcnt(0)" ::: "memory"); __builtin_amdgcn_s_barrier();
  group(95,false);

  #pragma unroll
  for (int r=0;r<8;r++){
    int row = m0 + wm*128 + r*16 + l4*4;
    #pragma unroll
    for (int c=0;c<3;c++){
      int col = n0 + wn*48 + c*16 + l15;
      float bv = bias[col];
      #pragma unroll
      for (int q=0;q<4;q++)
        C[(size_t)(row+q)*N + col] = f2bf(acc[r][c][q] + bv);
    }
  }
}

// ---------------- out-proj GEMM: 256x128 tile, BK=32 pairs, counted-vmcnt, f32 split epi ----
// grid 240 (10 M x 24 N) -> <=1 block/CU, single round. LDS 4 x (A 16KB + B 8KB) = 96KB.
// Loads/pair/thread = 3 (2A+1B). After issuing pair G+3: outstanding = 9 -> vmcnt(6)
// drains pair G+1. Tail: after 93 outstanding 6 -> vmcnt(3); after 94 -> vmcnt(0).
__global__ __launch_bounds__(512) void gemm_out_kernel(const u16* __restrict__ A,
                                                       const u16* __restrict__ Bt,
                                                       const float* __restrict__ bias,
                                                       float* __restrict__ Cf){
  const int K = 3072;
  __shared__ __align__(16) u16 lds[49152];   // 4 x 12288
  int tid = threadIdx.x, wv = tid>>6, lane = tid&63;
  int wm = wv>>2, wn = wv&3;
  int l15 = lane&15, l4 = lane>>4;

  int bid = blockIdx.x;                 // 240 = 8 XCD * 30
  int wg = (bid&7)*30 + (bid>>3);
  int bm = wg/24, bn = wg%24;
  int m0 = bm*256, n0 = bn*128;

  int rlane = lane>>2;
  int schn = (lane&3) ^ ((lane>>3)&3);
  const u16* aS = A  + (size_t)(m0 + wv*32 + rlane)*K + schn*8;
  const u16* bS = Bt + (size_t)(n0 + (tid>>2))*K + schn*8;

  auto stagePair = [&](int G){
    u16* base = lds + (G&3)*12288;
    size_t ko = (size_t)G*32;
    #pragma unroll
    for (int j=0;j<2;j++)
      __builtin_amdgcn_global_load_lds((gptr_t)(aS + (size_t)j*16*K + ko),
                                       (lptr_t)(base + (wv*2+j)*512), 16,0,0);
    __builtin_amdgcn_global_load_lds((gptr_t)(bS + ko),
                                     (lptr_t)(base + 8192 + wv*512), 16,0,0);
  };

  int fcs = l4 ^ ((l15>>1)&3);
  f32x4 acc[8][2];
  #pragma unroll
  for (int r=0;r<8;r++)
    #pragma unroll
    for (int c=0;c<2;c++)
      #pragma unroll
      for (int q=0;q<4;q++) acc[r][c][q] = 0.f;

  stagePair(0); stagePair(1); stagePair(2);
  asm volatile("s_waitcnt vmcnt(6)" ::: "memory");
  __builtin_amdgcn_s_barrier();

  auto group = [&](int G, bool issue){
    const u16* rA = lds + (G&3)*12288;
    const u16* rB = rA + 8192;
    bf16x8 af[8], bfv[2];
    #pragma unroll
    for (int r=0;r<8;r++) af[r] = *(const bf16x8*)(rA + (wm*128 + r*16 + l15)*32 + fcs*8);
    #pragma unroll
    for (int c=0;c<2;c++) bfv[c] = *(const bf16x8*)(rB + (wn*32 + c*16 + l15)*32 + fcs*8);
    if (issue) stagePair(G+3);
    __builtin_amdgcn_s_setprio(1);
    #pragma unroll
    for (int r=0;r<8;r++)
      #pragma unroll
      for (int c=0;c<2;c++)
        acc[r][c] = __builtin_amdgcn_mfma_f32_16x16x32_bf16(af[r], bfv[c], acc[r][c], 0,0,0);
    __builtin_amdgcn_s_setprio(0);
  };

  for (int G=0; G<93; ++G){
    group(G, true);
    asm volatile("s_waitcnt vmcnt(6)" ::: "memory");
    __builtin_amdgcn_s_barrier();
  }
  group(93,false); asm volatile("s_waitcnt vmcnt(3)" ::: "memory"); __builtin_amdgcn_s_barrier();
  group(94,false); asm volatile("s_waitcnt vmcnt(0)" ::: "memory"); __builtin_amdgcn_s_barrier();
  group(95,false);

  #pragma unroll
  for (int r=0;r<8;r++){
    int row = m0 + wm*128 + r*16 + l4*4;
    #pragma unroll
    for (int c=0;c<2;c++){
      int col = n0 + wn*32 + c*16 + l15;
      float bv = bias[col];
      #pragma unroll
      for (int q=0;q<4;q++){
        int rr = row + q;
        int bb = rr / 1280; int s = rr - bb*1280;
        float* dst = (s < 256) ? (Cf + 6291456 + ((size_t)(bb*256 + s))*3072)
                               : (Cf + ((size_t)(bb*1024 + (s-256)))*3072);
        dst[col] = acc[r][c][q] + bv;
      }
    }
  }
}

// ---------------- LayerNorm (no affine) + partial RoPE for Q,K ----------------
__device__ __forceinline__ void ln_head(const u16* __restrict__ in, u16* __restrict__ out,
                                        const float* __restrict__ cosb, const float* __restrict__ sinb,
                                        int lane, int s, float scale){
  float x0 = bf2f(in[lane]), x1 = bf2f(in[64+lane]);
  float sum = x0 + x1;
  #pragma unroll
  for (int off=32; off>=1; off>>=1) sum += __shfl_xor(sum, off);
  float mean = sum * 0.0078125f;
  float d0 = x0-mean, d1 = x1-mean;
  float vs = d0*d0 + d1*d1;
  #pragma unroll
  for (int off=32; off>=1; off>>=1) vs += __shfl_xor(vs, off);
  float rstd = rsqrtf(vs*0.0078125f + 1e-5f);
  float y0 = d0*rstd, y1 = d1*rstd;
  if (s >= 256){
    int p = s - 256;
    float c0 = cosb[p*128 + lane], c1 = cosb[p*128 + 64 + lane];
    float s0 = sinb[p*128 + lane], s1 = sinb[p*128 + 64 + lane];
    float t0 = y0*c0 - y1*s0;
    float t1 = y1*c1 + y0*s1;
    y0 = t0; y1 = t1;
  }
  out[lane]    = f2bf(y0*scale);
  out[64+lane] = f2bf(y1*scale);
}

__global__ __launch_bounds__(256) void ln_rope_kernel(const u16* __restrict__ qkv,
                                                      const float* __restrict__ cosb,
                                                      const float* __restrict__ sinb,
                                                      u16* __restrict__ Q, u16* __restrict__ Kd){
  int g = blockIdx.x*4 + (threadIdx.x>>6);
  int lane = threadIdx.x & 63;
  int h = g % 24; int m = g / 24;
  int b = m / 1280; int s = m - b*1280;
  const u16* base = qkv + (size_t)m*9216 + h*128;
  size_t ho = ((size_t)(b*24 + h)*1280 + s)*128;
  ln_head(base,        Q  + ho, cosb, sinb, lane, s, 0.12751512f); // (1/sqrt(128))*log2(e)
  ln_head(base + 3072, Kd + ho, cosb, sinb, lane, s, 1.0f);
}

// ---------------- V transpose: qkv v-region -> Vt [B*H][128][1280] bf16 ----------------
__global__ __launch_bounds__(256) void v_transpose_kernel(const u16* __restrict__ qkv,
                                                          u16* __restrict__ Vt){
  __shared__ u16 tl[16384];
  int tid = threadIdx.x;
  int blk = blockIdx.x;
  int st = blk % 10; int bh = blk / 10; int b = bh/24, h = bh - b*24;
  #pragma unroll
  for (int i=0;i<8;i++){
    int idx = i*256 + tid; int s = idx>>4, dc = idx&15;
    int m = b*1280 + st*128 + s;
    bf16x8 v = *(const bf16x8*)(qkv + (size_t)m*9216 + 6144 + h*128 + dc*8);
    *(bf16x8*)(tl + (s*16 + (dc ^ ((s>>3)&7)))*8) = v;
  }
  __syncthreads();
  #pragma unroll
  for (int i=0;i<8;i++){
    int idx = i*256 + tid; int d = idx>>4, sc = idx&15;
    union { u16 t[8]; bf16x8 v; } tmp;
    #pragma unroll
    for (int j=0;j<8;j++){
      int s = sc*8 + j;
      tmp.t[j] = tl[(s*16 + ((d>>3) ^ ((s>>3)&7)))*8 + (d&7)];
    }
    *(bf16x8*)(Vt + ((size_t)bh*128 + d)*1280 + st*128 + sc*8) = tmp.v;
  }
}

// ---------------- flash attention: 8 waves x 32 q = 256 q/block, dbuf K/V, vmcnt(4) ----
__global__ __launch_bounds__(512) void attn_kernel(const u16* __restrict__ Q,
                                                   const u16* __restrict__ Kg,
                                                   const u16* __restrict__ Vt,
                                                   u16* __restrict__ AO){
  __shared__ __align__(16) u16 smem[32768];  // 64KB: K0|K1|V0|V1 (8192 u16 each)
  int tid = threadIdx.x, wv = tid>>6, lane = tid&63;
  int l31 = lane & 31, hi = lane >> 5;
  int bid = blockIdx.x;                 // 240 = 8 XCD * 30
  int wg = (bid&7)*30 + (bid>>3);
  int qt = wg % 5; int bh = wg / 5;
  int b = bh / 24; int h = bh - b*24;
  const u16* Qb = Q  + (size_t)bh*1280*128;
  const u16* Kb = Kg + (size_t)bh*1280*128;
  const u16* Vb = Vt + (size_t)bh*128*1280;
  int q0 = qt*256 + wv*32;

  bf16x8 qf[8];
  #pragma unroll
  for (int ds=0; ds<8; ds++)
    qf[ds] = *(const bf16x8*)(Qb + (size_t)(q0 + l31)*128 + ds*16 + hi*8);

  f32x16 o[4];
  #pragma unroll
  for (int dc=0; dc<4; dc++)
    #pragma unroll
    for (int r=0;r<16;r++) o[dc][r] = 0.f;
  float mrun = -1e30f, lrun = 0.f;

  auto stage = [&](int t){
    int s0 = t*64; int bu = t&1;
    u16* Ksb = smem + bu*8192;
    u16* Vsb = smem + 16384 + bu*8192;
    #pragma unroll
    for (int i=0;i<2;i++){
      int c = i*512 + tid; int key = c>>4, dc16 = c&15;
      const u16* src = Kb + (size_t)(s0+key)*128 + ((dc16 ^ (key&7))<<3);
      __builtin_amdgcn_global_load_lds((gptr_t)src, (lptr_t)(Ksb + i*4096 + wv*512), 16, 0, 0);
    }
    #pragma unroll
    for (int i=0;i<2;i++){
      int c = i*512 + tid; int d = c>>3, kc = c&7;
      const u16* src = Vb + (size_t)d*1280 + s0 + ((kc ^ (d&7))<<3);
      __builtin_amdgcn_global_load_lds((gptr_t)src, (lptr_t)(Vsb + i*4096 + wv*512), 16, 0, 0);
    }
  };

  auto compute = [&](int t){
    const u16* Ks = smem + (t&1)*8192;
    const u16* Vs = smem + 16384 + (t&1)*8192;
    f32x16 sA, sB, sC, sD;
    #pragma unroll
    for (int r=0;r<16;r++){ sA[r]=0.f; sB[r]=0.f; sC[r]=0.f; sD[r]=0.f; }
    __builtin_amdgcn_s_setprio(1);
    #pragma unroll
    for (int dp=0; dp<4; dp++){            // 4 independent accumulation chains
      int dsE = 2*dp, dsO = 2*dp+1;
      int chE = dsE*2 + hi, chO = dsO*2 + hi;
      bf16x8 k0E = *(const bf16x8*)(Ks + (l31*16      + (chE ^ (l31 & 7)))*8);
      bf16x8 k1E = *(const bf16x8*)(Ks + ((32+l31)*16 + (chE ^ (l31 & 7)))*8);
      bf16x8 k0O = *(const bf16x8*)(Ks + (l31*16      + (chO ^ (l31 & 7)))*8);
      bf16x8 k1O = *(const bf16x8*)(Ks + ((32+l31)*16 + (chO ^ (l31 & 7)))*8);
      sA = __builtin_amdgcn_mfma_f32_32x32x16_bf16(k0E, qf[dsE], sA, 0,0,0);
      sC = __builtin_amdgcn_mfma_f32_32x32x16_bf16(k1E, qf[dsE], sC, 0,0,0);
      sB = __builtin_amdgcn_mfma_f32_32x32x16_bf16(k0O, qf[dsO], sB, 0,0,0);
      sD = __builtin_amdgcn_mfma_f32_32x32x16_bf16(k1O, qf[dsO], sD, 0,0,0);
    }
    __builtin_amdgcn_s_setprio(0);
    f32x16 sacc0, sacc1;
    #pragma unroll
    for (int r=0;r<16;r++){ sacc0[r] = sA[r]+sB[r]; sacc1[r] = sC[r]+sD[r]; }

    float mt = fmaxf(vmax16(sacc0), vmax16(sacc1));
    mt = fmaxf(mt, __shfl_xor(mt, 32));
    // defer-rescale (T13): skip o-rescale when tile max close to running max
    int noresc = __all(mt <= mrun + 11.5f);   // 8*log2(e)
    float mnew, corr;
    if (noresc){ mnew = mrun; corr = 1.f; }
    else       { mnew = fmaxf(mrun, mt); corr = fexp2(mrun - mnew); }
    mrun = mnew;
    float p[32];
    float ps0=0.f, ps1=0.f, ps2=0.f, ps3=0.f;
    #pragma unroll
    for (int r=0;r<8;r++){ p[r]    = fexp2(sacc0[r]   - mnew); ps0 += p[r]; }
    #pragma unroll
    for (int r=0;r<8;r++){ p[8+r]  = fexp2(sacc0[8+r] - mnew); ps1 += p[8+r]; }
    #pragma unroll
    for (int r=0;r<8;r++){ p[16+r] = fexp2(sacc1[r]   - mnew); ps2 += p[16+r]; }
    #pragma unroll
    for (int r=0;r<8;r++){ p[24+r] = fexp2(sacc1[8+r] - mnew); ps3 += p[24+r]; }
    float ps = (ps0+ps1) + (ps2+ps3);
    ps += __shfl_xor(ps, 32);
    lrun = lrun*corr + ps;
    if (!noresc){
      #pragma unroll
      for (int dc=0; dc<4; dc++)
        #pragma unroll
        for (int r=0;r<16;r++) o[dc][r] *= corr;
    }

    bf16x8 pf[4];
    #pragma unroll
    for (int c=0;c<4;c++){
      const float* pp = p + (c>>1)*16 + (c&1)*8;
      unsigned x0 = cvtpk_bf16(pp[0], pp[1]);
      unsigned y0 = cvtpk_bf16(pp[4], pp[5]);
      unsigned x1 = cvtpk_bf16(pp[2], pp[3]);
      unsigned y1 = cvtpk_bf16(pp[6], pp[7]);
      asm volatile("v_permlane32_swap_b32 %0, %1" : "+v"(x0), "+v"(y0));
      asm volatile("v_permlane32_swap_b32 %0, %1" : "+v"(x1), "+v"(y1));
      union { unsigned u[4]; bf16x8 v; } wb;
      wb.u[0]=x0; wb.u[1]=x1; wb.u[2]=y0; wb.u[3]=y1;
      pf[c] = wb.v;
    }
    __builtin_amdgcn_s_setprio(1);
    #pragma unroll
    for (int c=0;c<4;c++){
      #pragma unroll
      for (int dc=0;dc<4;dc++){
        int d = dc*32 + l31;
        bf16x8 vf = *(const bf16x8*)(Vs + (d*8 + ((2*c+hi) ^ (d&7)))*8);
        o[dc] = __builtin_amdgcn_mfma_f32_32x32x16_bf16(vf, pf[c], o[dc], 0,0,0);
      }
    }
    __builtin_amdgcn_s_setprio(0);
  };

  stage(0); stage(1);
  for (int t=0; t<19; ++t){
    asm volatile("s_waitcnt vmcnt(4)" ::: "memory");  // tile t landed; t+1 in flight
    __builtin_amdgcn_s_barrier();
    compute(t);
    __builtin_amdgcn_s_barrier();                     // all reads of buf[t&1] done
    if (t <= 17) stage(t+2);
  }
  asm volatile("s_waitcnt vmcnt(0)" ::: "memory");
  __builtin_amdgcn_s_barrier();
  compute(19);

  // epilogue: normalize, LDS-transpose per wave, coalesced bf16 store
  float rl = 1.f / lrun;
  __syncthreads();
  u16* ob = smem + wv*4096;
  #pragma unroll
  for (int dc=0; dc<4; dc++){
    #pragma unroll
    for (int rp=0; rp<8; rp++){
      int d = dc*32 + 2*(rp&1) + 8*(rp>>1) + 4*hi;
      unsigned u = cvtpk_bf16(o[dc][2*rp]*rl, o[dc][2*rp+1]*rl);
      int chs = (d>>3) ^ (l31 & 7);
      *(unsigned*)(ob + l31*128 + chs*8 + (d&7)) = u;
    }
  }
  __syncthreads();
  #pragma unroll
  for (int i=0;i<8;i++){
    int idx = i*64 + lane; int q = idx>>4, c8 = idx&15;
    bf16x8 vv = *(const bf16x8*)(ob + q*128 + ((c8 ^ (q&7))<<3));
    *(bf16x8*)(AO + (size_t)(b*1280 + q0 + q)*3072 + h*128 + c8*8) = vv;
  }
}

// ---------------- launch ----------------
extern "C" void kernel_launch(void* const* d_in, const int* in_sizes, int n_in,
                              void* d_out, int out_size, void* d_ws, size_t ws_size,
                              hipStream_t stream){
  (void)in_sizes; (void)n_in; (void)out_size; (void)ws_size;
  const float* hs   = (const float*)d_in[0];
  const float* ehs  = (const float*)d_in[1];
  const float* cosb = (const float*)d_in[2];
  const float* sinb = (const float*)d_in[3];
  const float* wqkv = (const float*)d_in[4];
  const float* bqkv = (const float*)d_in[5];
  const float* wout = (const float*)d_in[6];
  const float* bout = (const float*)d_in[7];
  char* w = (char*)d_ws;
  size_t o = 0;
  u16* Abf = (u16*)(w + o); o += 15728640ull;   // x concat bf16 [2560][3072]
  u16* WqT = (u16*)(w + o); o += 56623104ull;   // w_qkv^T bf16 [9216][3072]
  u16* WoT = (u16*)(w + o); o += 18874368ull;   // w_out^T bf16 [3072][3072]
  u16* qkv = (u16*)(w + o); o += 47185920ull;   // qkv bf16 [2560][9216]
  u16* Qd  = (u16*)(w + o); o += 15728640ull;   // Q [B*H][1280][128]
  u16* Kd  = (u16*)(w + o); o += 15728640ull;   // K [B*H][1280][128]
  u16* Vtd = (u16*)(w + o); o += 15728640ull;   // V^T [B*H][128][1280]
  u16* AO  = (u16*)(w + o);                     // attn out bf16 [2560][3072]
  float* out = (float*)d_out;

  prep_x_kernel<<<7680, 256, 0, stream>>>(hs, ehs, Abf);
  transpose_w_kernel<<<dim3(288,48), 256, 0, stream>>>(wqkv, WqT, 3072, 9216);
  transpose_w_kernel<<<dim3(96,48),  256, 0, stream>>>(wout, WoT, 3072, 3072);
  gemm_qkv_kernel<<<480, 512, 0, stream>>>(Abf, WqT, bqkv, qkv);
  ln_rope_kernel<<<15360, 256, 0, stream>>>(qkv, cosb, sinb, Qd, Kd);
  v_transpose_kernel<<<480, 256, 0, stream>>>(qkv, Vtd);
  attn_kernel<<<240, 512, 0, stream>>>(Qd, Kd, Vtd, AO);
  gemm_out_kernel<<<240, 512, 0, stream>>>(AO, WoT, bout, out);
}

// Round 7
// 517.137 us; speedup vs baseline: 1.1333x; 1.0044x over previous
//
#include <hip/hip_runtime.h>

typedef unsigned short u16;
typedef __attribute__((ext_vector_type(8))) short bf16x8;
typedef __attribute__((ext_vector_type(4))) float f32x4;
typedef __attribute__((ext_vector_type(16))) float f32x16;

typedef const __attribute__((address_space(1))) void* gptr_t;
typedef __attribute__((address_space(3))) void* lptr_t;

__device__ __forceinline__ unsigned cvtpk_bf16(float a, float b){
  unsigned r; asm("v_cvt_pk_bf16_f32 %0, %1, %2" : "=v"(r) : "v"(a), "v"(b)); return r;
}
__device__ __forceinline__ u16 f2bf(float x){ return (u16)cvtpk_bf16(x, x); }
__device__ __forceinline__ float bf2f(u16 u){ union{unsigned i; float f;} v; v.i = ((unsigned)u)<<16; return v.f; }
__device__ __forceinline__ float fexp2(float x){ float r; asm("v_exp_f32 %0, %1" : "=v"(r) : "v"(x)); return r; }
__device__ __forceinline__ float vmax16(f32x16 v){
  float a0 = fmaxf(v[0],v[1]),  a1 = fmaxf(v[2],v[3]),  a2 = fmaxf(v[4],v[5]),  a3 = fmaxf(v[6],v[7]);
  float a4 = fmaxf(v[8],v[9]),  a5 = fmaxf(v[10],v[11]),a6 = fmaxf(v[12],v[13]),a7 = fmaxf(v[14],v[15]);
  float b0 = fmaxf(a0,a1), b1 = fmaxf(a2,a3), b2 = fmaxf(a4,a5), b3 = fmaxf(a6,a7);
  return fmaxf(fmaxf(b0,b1), fmaxf(b2,b3));
}

// ---------------- prep: concat(enc, hid) -> bf16 A [2560][3072] ----------------
__global__ __launch_bounds__(256) void prep_x_kernel(const float* __restrict__ hs,
                                                     const float* __restrict__ ehs,
                                                     u16* __restrict__ A){
  int idx = blockIdx.x*256 + threadIdx.x;
  int v = idx*4;
  int m = v/3072, c = v - m*3072;
  int b = m/1280, s = m - b*1280;
  const float* src = (s < 256) ? (ehs + ((size_t)(b*256+s))*3072 + c)
                               : (hs  + ((size_t)(b*1024+(s-256)))*3072 + c);
  float4 f = *(const float4*)src;
  uint2 o; o.x = cvtpk_bf16(f.x, f.y); o.y = cvtpk_bf16(f.z, f.w);
  *(uint2*)(A + v) = o;
}

// ---------------- transpose W [K][N] f32 -> Wt [N][K] bf16 ----------------
__global__ __launch_bounds__(256) void transpose_w_kernel(const float* __restrict__ W,
                                                          u16* __restrict__ Wt,
                                                          int K, int N){
  __shared__ float t[64][36];
  int k0 = blockIdx.y*64, n0 = blockIdx.x*32;
  int tid = threadIdx.x;
  #pragma unroll
  for (int i=0;i<2;i++){
    int cell = i*256 + tid; int kl = cell>>3, nc = cell&7;
    *(float4*)&t[kl][nc*4] = *(const float4*)&W[(size_t)(k0+kl)*N + n0 + nc*4];
  }
  __syncthreads();
  #pragma unroll
  for (int i=0;i<2;i++){
    int chunk = i*256 + tid; int nl = chunk>>4, kc = chunk&15;
    float a = t[kc*4+0][nl], b2 = t[kc*4+1][nl], c2 = t[kc*4+2][nl], d2 = t[kc*4+3][nl];
    uint2 u; u.x = cvtpk_bf16(a, b2); u.y = cvtpk_bf16(c2, d2);
    *(uint2*)&Wt[(size_t)(n0+nl)*K + k0 + kc*4] = u;
  }
}

// ---------------- QKV GEMM: 256x192 tile, BK=32 pairs, counted-vmcnt pipeline ----------
// Waves 4x2 (wm 0..3, wn 0..1): per-wave 64x96. LDS read/group = 2x256+4x192 rows
// = 80KB (vs 88KB at 2x4) -> LDS-port-bound model predicts ~-18% group time.
__global__ __launch_bounds__(512) void gemm_qkv_kernel(const u16* __restrict__ A,
                                                       const u16* __restrict__ Bt,
                                                       const float* __restrict__ bias,
                                                       u16* __restrict__ C){
  const int K = 3072, N = 9216;
  __shared__ __align__(16) u16 lds[57344];   // 4 x 14336
  int tid = threadIdx.x, wv = tid>>6, lane = tid&63;
  int wm = wv>>1, wn = wv&1;
  int l15 = lane&15, l4 = lane>>4;

  int bid = blockIdx.x;                 // 480 = 8 XCD * 60
  int wg = (bid&7)*60 + (bid>>3);
  int bm = wg/48, bn = wg%48;
  int m0 = bm*256, n0 = bn*192;

  int rlane = lane>>2;
  int schn = (lane&3) ^ ((lane>>3)&3);
  const u16* aS = A + (size_t)(m0 + wv*32 + rlane)*K + schn*8;
  int brow = n0 + wv*32 + rlane; if (brow > 9215) brow = 9215;
  const u16* bS = Bt + (size_t)brow*K + schn*8;

  auto stagePair = [&](int G){
    u16* base = lds + (G&3)*14336;
    size_t ko = (size_t)G*32;
    #pragma unroll
    for (int j=0;j<2;j++)
      __builtin_amdgcn_global_load_lds((gptr_t)(aS + (size_t)j*16*K + ko),
                                       (lptr_t)(base + (wv*2+j)*512), 16,0,0);
    if (wv < 6){
      #pragma unroll
      for (int j=0;j<2;j++)
        __builtin_amdgcn_global_load_lds((gptr_t)(bS + (size_t)j*16*K + ko),
                                         (lptr_t)(base + 8192 + (wv*2+j)*512), 16,0,0);
    }
  };

  int fcs = l4 ^ ((l15>>1)&3);
  f32x4 acc[4][6];
  #pragma unroll
  for (int r=0;r<4;r++)
    #pragma unroll
    for (int c=0;c<6;c++)
      #pragma unroll
      for (int q=0;q<4;q++) acc[r][c][q] = 0.f;

  stagePair(0); stagePair(1); stagePair(2);
  asm volatile("s_waitcnt vmcnt(4)" ::: "memory");
  __builtin_amdgcn_s_barrier();

  auto group = [&](int G, bool issue){
    const u16* rA = lds + (G&3)*14336;
    const u16* rB = rA + 8192;
    bf16x8 af[4], bfv[6];
    #pragma unroll
    for (int r=0;r<4;r++) af[r] = *(const bf16x8*)(rA + (wm*64 + r*16 + l15)*32 + fcs*8);
    #pragma unroll
    for (int c=0;c<6;c++) bfv[c] = *(const bf16x8*)(rB + (wn*96 + c*16 + l15)*32 + fcs*8);
    if (issue) stagePair(G+3);
    __builtin_amdgcn_s_setprio(1);
    #pragma unroll
    for (int r=0;r<4;r++)
      #pragma unroll
      for (int c=0;c<6;c++)
        acc[r][c] = __builtin_amdgcn_mfma_f32_16x16x32_bf16(af[r], bfv[c], acc[r][c], 0,0,0);
    __builtin_amdgcn_s_setprio(0);
  };

  for (int G=0; G<93; ++G){
    group(G, true);
    asm volatile("s_waitcnt vmcnt(4)" ::: "memory");
    __builtin_amdgcn_s_barrier();
  }
  group(93,false); asm volatile("s_waitcnt vmcnt(2)" ::: "memory"); __builtin_amdgcn_s_barrier();
  group(94,false); asm volatile("s_waitcnt vmcnt(0)" ::: "memory"); __builtin_amdgcn_s_barrier();
  group(95,false);

  #pragma unroll
  for (int r=0;r<4;r++){
    int row = m0 + wm*64 + r*16 + l4*4;
    #pragma unroll
    for (int c=0;c<6;c++){
      int col = n0 + wn*96 + c*16 + l15;
      float bv = bias[col];
      #pragma unroll
      for (int q=0;q<4;q++)
        C[(size_t)(row+q)*N + col] = f2bf(acc[r][c][q] + bv);
    }
  }
}

// ---------------- out-proj GEMM: 256x128 tile, BK=32 pairs, counted-vmcnt, f32 split epi ----
// Waves 4x2: per-wave 64x64. LDS read/group = 2x256+4x128 rows = 64KB (vs 80KB).
__global__ __launch_bounds__(512) void gemm_out_kernel(const u16* __restrict__ A,
                                                       const u16* __restrict__ Bt,
                                                       const float* __restrict__ bias,
                                                       float* __restrict__ Cf){
  const int K = 3072;
  __shared__ __align__(16) u16 lds[49152];   // 4 x 12288
  int tid = threadIdx.x, wv = tid>>6, lane = tid&63;
  int wm = wv>>1, wn = wv&1;
  int l15 = lane&15, l4 = lane>>4;

  int bid = blockIdx.x;                 // 240 = 8 XCD * 30
  int wg = (bid&7)*30 + (bid>>3);
  int bm = wg/24, bn = wg%24;
  int m0 = bm*256, n0 = bn*128;

  int rlane = lane>>2;
  int schn = (lane&3) ^ ((lane>>3)&3);
  const u16* aS = A  + (size_t)(m0 + wv*32 + rlane)*K + schn*8;
  const u16* bS = Bt + (size_t)(n0 + (tid>>2))*K + schn*8;

  auto stagePair = [&](int G){
    u16* base = lds + (G&3)*12288;
    size_t ko = (size_t)G*32;
    #pragma unroll
    for (int j=0;j<2;j++)
      __builtin_amdgcn_global_load_lds((gptr_t)(aS + (size_t)j*16*K + ko),
                                       (lptr_t)(base + (wv*2+j)*512), 16,0,0);
    __builtin_amdgcn_global_load_lds((gptr_t)(bS + ko),
                                     (lptr_t)(base + 8192 + wv*512), 16,0,0);
  };

  int fcs = l4 ^ ((l15>>1)&3);
  f32x4 acc[4][4];
  #pragma unroll
  for (int r=0;r<4;r++)
    #pragma unroll
    for (int c=0;c<4;c++)
      #pragma unroll
      for (int q=0;q<4;q++) acc[r][c][q] = 0.f;

  stagePair(0); stagePair(1); stagePair(2);
  asm volatile("s_waitcnt vmcnt(6)" ::: "memory");
  __builtin_amdgcn_s_barrier();

  auto group = [&](int G, bool issue){
    const u16* rA = lds + (G&3)*12288;
    const u16* rB = rA + 8192;
    bf16x8 af[4], bfv[4];
    #pragma unroll
    for (int r=0;r<4;r++) af[r] = *(const bf16x8*)(rA + (wm*64 + r*16 + l15)*32 + fcs*8);
    #pragma unroll
    for (int c=0;c<4;c++) bfv[c] = *(const bf16x8*)(rB + (wn*64 + c*16 + l15)*32 + fcs*8);
    if (issue) stagePair(G+3);
    __builtin_amdgcn_s_setprio(1);
    #pragma unroll
    for (int r=0;r<4;r++)
      #pragma unroll
      for (int c=0;c<4;c++)
        acc[r][c] = __builtin_amdgcn_mfma_f32_16x16x32_bf16(af[r], bfv[c], acc[r][c], 0,0,0);
    __builtin_amdgcn_s_setprio(0);
  };

  for (int G=0; G<93; ++G){
    group(G, true);
    asm volatile("s_waitcnt vmcnt(6)" ::: "memory");
    __builtin_amdgcn_s_barrier();
  }
  group(93,false); asm volatile("s_waitcnt vmcnt(3)" ::: "memory"); __builtin_amdgcn_s_barrier();
  group(94,false); asm volatile("s_waitcnt vmcnt(0)" ::: "memory"); __builtin_amdgcn_s_barrier();
  group(95,false);

  #pragma unroll
  for (int r=0;r<4;r++){
    int row = m0 + wm*64 + r*16 + l4*4;
    #pragma unroll
    for (int c=0;c<4;c++){
      int col = n0 + wn*64 + c*16 + l15;
      float bv = bias[col];
      #pragma unroll
      for (int q=0;q<4;q++){
        int rr = row + q;
        int bb = rr / 1280; int s = rr - bb*1280;
        float* dst = (s < 256) ? (Cf + 6291456 + ((size_t)(bb*256 + s))*3072)
                               : (Cf + ((size_t)(bb*1024 + (s-256)))*3072);
        dst[col] = acc[r][c][q] + bv;
      }
    }
  }
}

// ---------------- LayerNorm (no affine) + partial RoPE for Q,K ----------------
__device__ __forceinline__ void ln_head(const u16* __restrict__ in, u16* __restrict__ out,
                                        const float* __restrict__ cosb, const float* __restrict__ sinb,
                                        int lane, int s, float scale){
  float x0 = bf2f(in[lane]), x1 = bf2f(in[64+lane]);
  float sum = x0 + x1;
  #pragma unroll
  for (int off=32; off>=1; off>>=1) sum += __shfl_xor(sum, off);
  float mean = sum * 0.0078125f;
  float d0 = x0-mean, d1 = x1-mean;
  float vs = d0*d0 + d1*d1;
  #pragma unroll
  for (int off=32; off>=1; off>>=1) vs += __shfl_xor(vs, off);
  float rstd = rsqrtf(vs*0.0078125f + 1e-5f);
  float y0 = d0*rstd, y1 = d1*rstd;
  if (s >= 256){
    int p = s - 256;
    float c0 = cosb[p*128 + lane], c1 = cosb[p*128 + 64 + lane];
    float s0 = sinb[p*128 + lane], s1 = sinb[p*128 + 64 + lane];
    float t0 = y0*c0 - y1*s0;
    float t1 = y1*c1 + y0*s1;
    y0 = t0; y1 = t1;
  }
  out[lane]    = f2bf(y0*scale);
  out[64+lane] = f2bf(y1*scale);
}

__global__ __launch_bounds__(256) void ln_rope_kernel(const u16* __restrict__ qkv,
                                                      const float* __restrict__ cosb,
                                                      const float* __restrict__ sinb,
                                                      u16* __restrict__ Q, u16* __restrict__ Kd){
  int g = blockIdx.x*4 + (threadIdx.x>>6);
  int lane = threadIdx.x & 63;
  int h = g % 24; int m = g / 24;
  int b = m / 1280; int s = m - b*1280;
  const u16* base = qkv + (size_t)m*9216 + h*128;
  size_t ho = ((size_t)(b*24 + h)*1280 + s)*128;
  ln_head(base,        Q  + ho, cosb, sinb, lane, s, 0.12751512f); // (1/sqrt(128))*log2(e)
  ln_head(base + 3072, Kd + ho, cosb, sinb, lane, s, 1.0f);
}

// ---------------- V transpose: qkv v-region -> Vt [B*H][128][1280] bf16 ----------------
__global__ __launch_bounds__(256) void v_transpose_kernel(const u16* __restrict__ qkv,
                                                          u16* __restrict__ Vt){
  __shared__ u16 tl[16384];
  int tid = threadIdx.x;
  int blk = blockIdx.x;
  int st = blk % 10; int bh = blk / 10; int b = bh/24, h = bh - b*24;
  #pragma unroll
  for (int i=0;i<8;i++){
    int idx = i*256 + tid; int s = idx>>4, dc = idx&15;
    int m = b*1280 + st*128 + s;
    bf16x8 v = *(const bf16x8*)(qkv + (size_t)m*9216 + 6144 + h*128 + dc*8);
    *(bf16x8*)(tl + (s*16 + (dc ^ ((s>>3)&7)))*8) = v;
  }
  __syncthreads();
  #pragma unroll
  for (int i=0;i<8;i++){
    int idx = i*256 + tid; int d = idx>>4, sc = idx&15;
    union { u16 t[8]; bf16x8 v; } tmp;
    #pragma unroll
    for (int j=0;j<8;j++){
      int s = sc*8 + j;
      tmp.t[j] = tl[(s*16 + ((d>>3) ^ ((s>>3)&7)))*8 + (d&7)];
    }
    *(bf16x8*)(Vt + ((size_t)bh*128 + d)*1280 + st*128 + sc*8) = tmp.v;
  }
}

// ---------------- flash attention: 8 waves x 32 q = 256 q/block, dbuf K/V, vmcnt(4) ----
__global__ __launch_bounds__(512) void attn_kernel(const u16* __restrict__ Q,
                                                   const u16* __restrict__ Kg,
                                                   const u16* __restrict__ Vt,
                                                   u16* __restrict__ AO){
  __shared__ __align__(16) u16 smem[32768];  // 64KB: K0|K1|V0|V1 (8192 u16 each)
  int tid = threadIdx.x, wv = tid>>6, lane = tid&63;
  int l31 = lane & 31, hi = lane >> 5;
  int bid = blockIdx.x;                 // 240 = 8 XCD * 30
  int wg = (bid&7)*30 + (bid>>3);
  int qt = wg % 5; int bh = wg / 5;
  int b = bh / 24; int h = bh - b*24;
  const u16* Qb = Q  + (size_t)bh*1280*128;
  const u16* Kb = Kg + (size_t)bh*1280*128;
  const u16* Vb = Vt + (size_t)bh*128*1280;
  int q0 = qt*256 + wv*32;

  bf16x8 qf[8];
  #pragma unroll
  for (int ds=0; ds<8; ds++)
    qf[ds] = *(const bf16x8*)(Qb + (size_t)(q0 + l31)*128 + ds*16 + hi*8);

  f32x16 o[4];
  #pragma unroll
  for (int dc=0; dc<4; dc++)
    #pragma unroll
    for (int r=0;r<16;r++) o[dc][r] = 0.f;
  float mrun = -1e30f, lrun = 0.f;

  auto stage = [&](int t){
    int s0 = t*64; int bu = t&1;
    u16* Ksb = smem + bu*8192;
    u16* Vsb = smem + 16384 + bu*8192;
    #pragma unroll
    for (int i=0;i<2;i++){
      int c = i*512 + tid; int key = c>>4, dc16 = c&15;
      const u16* src = Kb + (size_t)(s0+key)*128 + ((dc16 ^ (key&7))<<3);
      __builtin_amdgcn_global_load_lds((gptr_t)src, (lptr_t)(Ksb + i*4096 + wv*512), 16, 0, 0);
    }
    #pragma unroll
    for (int i=0;i<2;i++){
      int c = i*512 + tid; int d = c>>3, kc = c&7;
      const u16* src = Vb + (size_t)d*1280 + s0 + ((kc ^ (d&7))<<3);
      __builtin_amdgcn_global_load_lds((gptr_t)src, (lptr_t)(Vsb + i*4096 + wv*512), 16, 0, 0);
    }
  };

  auto compute = [&](int t){
    const u16* Ks = smem + (t&1)*8192;
    const u16* Vs = smem + 16384 + (t&1)*8192;
    f32x16 sA, sB, sC, sD;
    #pragma unroll
    for (int r=0;r<16;r++){ sA[r]=0.f; sB[r]=0.f; sC[r]=0.f; sD[r]=0.f; }
    __builtin_amdgcn_s_setprio(1);
    #pragma unroll
    for (int dp=0; dp<4; dp++){            // 4 independent accumulation chains
      int dsE = 2*dp, dsO = 2*dp+1;
      int chE = dsE*2 + hi, chO = dsO*2 + hi;
      bf16x8 k0E = *(const bf16x8*)(Ks + (l31*16      + (chE ^ (l31 & 7)))*8);
      bf16x8 k1E = *(const bf16x8*)(Ks + ((32+l31)*16 + (chE ^ (l31 & 7)))*8);
      bf16x8 k0O = *(const bf16x8*)(Ks + (l31*16      + (chO ^ (l31 & 7)))*8);
      bf16x8 k1O = *(const bf16x8*)(Ks + ((32+l31)*16 + (chO ^ (l31 & 7)))*8);
      sA = __builtin_amdgcn_mfma_f32_32x32x16_bf16(k0E, qf[dsE], sA, 0,0,0);
      sC = __builtin_amdgcn_mfma_f32_32x32x16_bf16(k1E, qf[dsE], sC, 0,0,0);
      sB = __builtin_amdgcn_mfma_f32_32x32x16_bf16(k0O, qf[dsO], sB, 0,0,0);
      sD = __builtin_amdgcn_mfma_f32_32x32x16_bf16(k1O, qf[dsO], sD, 0,0,0);
    }
    __builtin_amdgcn_s_setprio(0);
    f32x16 sacc0, sacc1;
    #pragma unroll
    for (int r=0;r<16;r++){ sacc0[r] = sA[r]+sB[r]; sacc1[r] = sC[r]+sD[r]; }

    float mt = fmaxf(vmax16(sacc0), vmax16(sacc1));
    mt = fmaxf(mt, __shfl_xor(mt, 32));
    // defer-rescale (T13): skip o-rescale when tile max close to running max
    int noresc = __all(mt <= mrun + 11.5f);   // 8*log2(e)
    float mnew, corr;
    if (noresc){ mnew = mrun; corr = 1.f; }
    else       { mnew = fmaxf(mrun, mt); corr = fexp2(mrun - mnew); }
    mrun = mnew;
    float p[32];
    float ps0=0.f, ps1=0.f, ps2=0.f, ps3=0.f;
    #pragma unroll
    for (int r=0;r<8;r++){ p[r]    = fexp2(sacc0[r]   - mnew); ps0 += p[r]; }
    #pragma unroll
    for (int r=0;r<8;r++){ p[8+r]  = fexp2(sacc0[8+r] - mnew); ps1 += p[8+r]; }
    #pragma unroll
    for (int r=0;r<8;r++){ p[16+r] = fexp2(sacc1[r]   - mnew); ps2 += p[16+r]; }
    #pragma unroll
    for (int r=0;r<8;r++){ p[24+r] = fexp2(sacc1[8+r] - mnew); ps3 += p[24+r]; }
    float ps = (ps0+ps1) + (ps2+ps3);
    ps += __shfl_xor(ps, 32);
    lrun = lrun*corr + ps;
    if (!noresc){
      #pragma unroll
      for (int dc=0; dc<4; dc++)
        #pragma unroll
        for (int r=0;r<16;r++) o[dc][r] *= corr;
    }

    bf16x8 pf[4];
    #pragma unroll
    for (int c=0;c<4;c++){
      const float* pp = p + (c>>1)*16 + (c&1)*8;
      unsigned x0 = cvtpk_bf16(pp[0], pp[1]);
      unsigned y0 = cvtpk_bf16(pp[4], pp[5]);
      unsigned x1 = cvtpk_bf16(pp[2], pp[3]);
      unsigned y1 = cvtpk_bf16(pp[6], pp[7]);
      asm volatile("v_permlane32_swap_b32 %0, %1" : "+v"(x0), "+v"(y0));
      asm volatile("v_permlane32_swap_b32 %0, %1" : "+v"(x1), "+v"(y1));
      union { unsigned u[4]; bf16x8 v; } wb;
      wb.u[0]=x0; wb.u[1]=x1; wb.u[2]=y0; wb.u[3]=y1;
      pf[c] = wb.v;
    }
    __builtin_amdgcn_s_setprio(1);
    #pragma unroll
    for (int c=0;c<4;c++){
      #pragma unroll
      for (int dc=0;dc<4;dc++){
        int d = dc*32 + l31;
        bf16x8 vf = *(const bf16x8*)(Vs + (d*8 + ((2*c+hi) ^ (d&7)))*8);
        o[dc] = __builtin_amdgcn_mfma_f32_32x32x16_bf16(vf, pf[c], o[dc], 0,0,0);
      }
    }
    __builtin_amdgcn_s_setprio(0);
  };

  stage(0); stage(1);
  for (int t=0; t<19; ++t){
    asm volatile("s_waitcnt vmcnt(4)" ::: "memory");  // tile t landed; t+1 in flight
    __builtin_amdgcn_s_barrier();
    compute(t);
    __builtin_amdgcn_s_barrier();                     // all reads of buf[t&1] done
    if (t <= 17) stage(t+2);
  }
  asm volatile("s_waitcnt vmcnt(0)" ::: "memory");
  __builtin_amdgcn_s_barrier();
  compute(19);

  // epilogue: normalize, LDS-transpose per wave, coalesced bf16 store
  float rl = 1.f / lrun;
  __syncthreads();
  u16* ob = smem + wv*4096;
  #pragma unroll
  for (int dc=0; dc<4; dc++){
    #pragma unroll
    for (int rp=0; rp<8; rp++){
      int d = dc*32 + 2*(rp&1) + 8*(rp>>1) + 4*hi;
      unsigned u = cvtpk_bf16(o[dc][2*rp]*rl, o[dc][2*rp+1]*rl);
      int chs = (d>>3) ^ (l31 & 7);
      *(unsigned*)(ob + l31*128 + chs*8 + (d&7)) = u;
    }
  }
  __syncthreads();
  #pragma unroll
  for (int i=0;i<8;i++){
    int idx = i*64 + lane; int q = idx>>4, c8 = idx&15;
    bf16x8 vv = *(const bf16x8*)(ob + q*128 + ((c8 ^ (q&7))<<3));
    *(bf16x8*)(AO + (size_t)(b*1280 + q0 + q)*3072 + h*128 + c8*8) = vv;
  }
}

// ---------------- launch ----------------
extern "C" void kernel_launch(void* const* d_in, const int* in_sizes, int n_in,
                              void* d_out, int out_size, void* d_ws, size_t ws_size,
                              hipStream_t stream){
  (void)in_sizes; (void)n_in; (void)out_size; (void)ws_size;
  const float* hs   = (const float*)d_in[0];
  const float* ehs  = (const float*)d_in[1];
  const float* cosb = (const float*)d_in[2];
  const float* sinb = (const float*)d_in[3];
  const float* wqkv = (const float*)d_in[4];
  const float* bqkv = (const float*)d_in[5];
  const float* wout = (const float*)d_in[6];
  const float* bout = (const float*)d_in[7];
  char* w = (char*)d_ws;
  size_t o = 0;
  u16* Abf = (u16*)(w + o); o += 15728640ull;   // x concat bf16 [2560][3072]
  u16* WqT = (u16*)(w + o); o += 56623104ull;   // w_qkv^T bf16 [9216][3072]
  u16* WoT = (u16*)(w + o); o += 18874368ull;   // w_out^T bf16 [3072][3072]
  u16* qkv = (u16*)(w + o); o += 47185920ull;   // qkv bf16 [2560][9216]
  u16* Qd  = (u16*)(w + o); o += 15728640ull;   // Q [B*H][1280][128]
  u16* Kd  = (u16*)(w + o); o += 15728640ull;   // K [B*H][1280][128]
  u16* Vtd = (u16*)(w + o); o += 15728640ull;   // V^T [B*H][128][1280]
  u16* AO  = (u16*)(w + o);                     // attn out bf16 [2560][3072]
  float* out = (float*)d_out;

  prep_x_kernel<<<7680, 256, 0, stream>>>(hs, ehs, Abf);
  transpose_w_kernel<<<dim3(288,48), 256, 0, stream>>>(wqkv, WqT, 3072, 9216);
  transpose_w_kernel<<<dim3(96,48),  256, 0, stream>>>(wout, WoT, 3072, 3072);
  gemm_qkv_kernel<<<480, 512, 0, stream>>>(Abf, WqT, bqkv, qkv);
  ln_rope_kernel<<<15360, 256, 0, stream>>>(qkv, cosb, sinb, Qd, Kd);
  v_transpose_kernel<<<480, 256, 0, stream>>>(qkv, Vtd);
  attn_kernel<<<240, 512, 0, stream>>>(Qd, Kd, Vtd, AO);
  gemm_out_kernel<<<240, 512, 0, stream>>>(AO, WoT, bout, out);
}